// Round 1
// baseline (3829.602 us; speedup 1.0000x reference)
//
#include <hip/hip_runtime.h>
#include <hip/hip_bf16.h>

// GPT forward: B=2, S=1024, E=512, H=8, D=64, L=4, FF=2048, V=32000
// fp32 baseline: tiled fp32 GEMMs + fused epilogues + flash-ish attention.

#define B_ 2
#define S_ 1024
#define E_ 512
#define H_ 8
#define D_ 64
#define L_ 4
#define FF_ 2048
#define V_ 32000
#define M_ (B_ * S_)          // 2048 rows
#define QKV_N (3 * H_ * D_)   // 1536

// ---------------- embed: h = tok_emb[x] + pos_emb ----------------
__global__ __launch_bounds__(256) void embed_kernel(
    const int* __restrict__ x, const float* __restrict__ tok,
    const float* __restrict__ pos, float* __restrict__ h) {
  int idx = blockIdx.x * 256 + threadIdx.x;           // over B*S*E = 2,097,152
  int e = idx & (E_ - 1);
  int t = (idx >> 9) & (S_ - 1);
  int b = idx >> 19;
  int tokid = x[b * S_ + t];
  h[idx] = tok[(size_t)tokid * E_ + e] + pos[(size_t)t * E_ + e];
}

// ---------------- pack QKV weights [L][H][E][D] -> [L][E][3*H*D] ----------------
__global__ __launch_bounds__(256) void pack_w_kernel(
    const float* __restrict__ Wq, const float* __restrict__ Wk,
    const float* __restrict__ Wv, float* __restrict__ Wp) {
  int idx = blockIdx.x * 256 + threadIdx.x;           // L*E*1536
  int n = idx % QKV_N;
  int r = idx / QKV_N;
  int e = r % E_;
  int l = r / E_;
  int t = n / (H_ * D_);
  int hd = n % (H_ * D_);
  int hh = hd >> 6, d = hd & 63;
  const float* src = (t == 0) ? Wq : (t == 1) ? Wk : Wv;
  Wp[idx] = src[(((size_t)l * H_ + hh) * E_ + e) * D_ + d];
}

__global__ __launch_bounds__(256) void pack_b_kernel(
    const float* __restrict__ bq, const float* __restrict__ bk,
    const float* __restrict__ bv, float* __restrict__ bp) {
  int idx = blockIdx.x * 256 + threadIdx.x;           // L*1536
  if (idx >= L_ * QKV_N) return;
  int n = idx % QKV_N;
  int l = idx / QKV_N;
  int t = n / (H_ * D_);
  int hd = n % (H_ * D_);
  const float* src = (t == 0) ? bq : (t == 1) ? bk : bv;
  bp[idx] = src[(size_t)l * H_ * D_ + hd];
}

// ---------------- GEMM 64x64 tile, 4x4 micro-tile ----------------
template <bool RELU>
__global__ __launch_bounds__(256) void gemm64_kernel(
    const float* __restrict__ A, const float* __restrict__ W,
    const float* __restrict__ bias, const float* __restrict__ resid,
    float* __restrict__ C, int M, int N, int K) {
  __shared__ __align__(16) float As[16][68];
  __shared__ __align__(16) float Bs[16][68];
  int tid = threadIdx.x;
  int tx = tid & 15, ty = tid >> 4;
  int col0 = blockIdx.x * 64, row0 = blockIdx.y * 64;

  int ar = tid >> 2, ak = (tid & 3) * 4;   // A: 64 rows x 16 k
  int bk = tid >> 4, bn = (tid & 15) * 4;  // B: 16 k x 64 cols

  const float* Ap = A + (size_t)(row0 + ar) * K + ak;
  const float* Wp = W + (size_t)bk * N + col0 + bn;

  float acc[4][4] = {};

  for (int k0 = 0; k0 < K; k0 += 16) {
    float4 a = *(const float4*)(Ap + k0);
    float4 w = *(const float4*)(Wp + (size_t)k0 * N);
    As[ak + 0][ar] = a.x; As[ak + 1][ar] = a.y;
    As[ak + 2][ar] = a.z; As[ak + 3][ar] = a.w;
    *(float4*)&Bs[bk][bn] = w;
    __syncthreads();
#pragma unroll
    for (int k = 0; k < 16; ++k) {
      float4 av = *(const float4*)&As[k][ty * 4];
      float4 bv = *(const float4*)&Bs[k][tx * 4];
      float af[4] = {av.x, av.y, av.z, av.w};
      float bf[4] = {bv.x, bv.y, bv.z, bv.w};
#pragma unroll
      for (int i = 0; i < 4; i++)
#pragma unroll
        for (int j = 0; j < 4; j++) acc[i][j] += af[i] * bf[j];
    }
    __syncthreads();
  }

#pragma unroll
  for (int i = 0; i < 4; i++) {
    int r = row0 + ty * 4 + i;
    int c = col0 + tx * 4;
    float4 bb = *(const float4*)&bias[c];
    float4 v = {acc[i][0] + bb.x, acc[i][1] + bb.y, acc[i][2] + bb.z, acc[i][3] + bb.w};
    if (resid) {
      float4 rr = *(const float4*)&resid[(size_t)r * N + c];
      v.x += rr.x; v.y += rr.y; v.z += rr.z; v.w += rr.w;
    }
    if (RELU) {
      v.x = fmaxf(v.x, 0.f); v.y = fmaxf(v.y, 0.f);
      v.z = fmaxf(v.z, 0.f); v.w = fmaxf(v.w, 0.f);
    }
    *(float4*)&C[(size_t)r * N + c] = v;
  }
}

// ---------------- GEMM 128x128 tile, 8x8 micro-tile ----------------
template <bool RELU>
__global__ __launch_bounds__(256) void gemm128_kernel(
    const float* __restrict__ A, const float* __restrict__ W,
    const float* __restrict__ bias, const float* __restrict__ resid,
    float* __restrict__ C, int M, int N, int K) {
  __shared__ __align__(16) float As[16][132];
  __shared__ __align__(16) float Bs[16][132];
  int tid = threadIdx.x;
  int tx = tid & 15, ty = tid >> 4;
  int col0 = blockIdx.x * 128, row0 = blockIdx.y * 128;

  int ar = tid >> 1, ak = (tid & 1) * 8;   // A: 128 rows x 16 k, 8 floats/thread
  int bk = tid >> 4, bn = (tid & 15) * 8;  // B: 16 k x 128 cols, 8 floats/thread

  const float* Ap = A + (size_t)(row0 + ar) * K + ak;
  const float* Wp = W + (size_t)bk * N + col0 + bn;

  float acc[8][8] = {};

  for (int k0 = 0; k0 < K; k0 += 16) {
    float4 a0 = *(const float4*)(Ap + k0);
    float4 a1 = *(const float4*)(Ap + k0 + 4);
    float4 w0 = *(const float4*)(Wp + (size_t)k0 * N);
    float4 w1 = *(const float4*)(Wp + (size_t)k0 * N + 4);
    As[ak + 0][ar] = a0.x; As[ak + 1][ar] = a0.y;
    As[ak + 2][ar] = a0.z; As[ak + 3][ar] = a0.w;
    As[ak + 4][ar] = a1.x; As[ak + 5][ar] = a1.y;
    As[ak + 6][ar] = a1.z; As[ak + 7][ar] = a1.w;
    *(float4*)&Bs[bk][bn] = w0;
    *(float4*)&Bs[bk][bn + 4] = w1;
    __syncthreads();
#pragma unroll
    for (int k = 0; k < 16; ++k) {
      float4 a0v = *(const float4*)&As[k][ty * 4];
      float4 a1v = *(const float4*)&As[k][64 + ty * 4];
      float4 b0v = *(const float4*)&Bs[k][tx * 4];
      float4 b1v = *(const float4*)&Bs[k][64 + tx * 4];
      float af[8] = {a0v.x, a0v.y, a0v.z, a0v.w, a1v.x, a1v.y, a1v.z, a1v.w};
      float bf[8] = {b0v.x, b0v.y, b0v.z, b0v.w, b1v.x, b1v.y, b1v.z, b1v.w};
#pragma unroll
      for (int i = 0; i < 8; i++)
#pragma unroll
        for (int j = 0; j < 8; j++) acc[i][j] += af[i] * bf[j];
    }
    __syncthreads();
  }

#pragma unroll
  for (int i = 0; i < 8; i++) {
    int r = row0 + ((i < 4) ? (ty * 4 + i) : (64 + ty * 4 + i - 4));
    int c0 = col0 + tx * 4;
    int c1 = col0 + 64 + tx * 4;
    float4 b0 = *(const float4*)&bias[c0];
    float4 b1 = *(const float4*)&bias[c1];
    float4 v0 = {acc[i][0] + b0.x, acc[i][1] + b0.y, acc[i][2] + b0.z, acc[i][3] + b0.w};
    float4 v1 = {acc[i][4] + b1.x, acc[i][5] + b1.y, acc[i][6] + b1.z, acc[i][7] + b1.w};
    if (resid) {
      float4 r0 = *(const float4*)&resid[(size_t)r * N + c0];
      float4 r1 = *(const float4*)&resid[(size_t)r * N + c1];
      v0.x += r0.x; v0.y += r0.y; v0.z += r0.z; v0.w += r0.w;
      v1.x += r1.x; v1.y += r1.y; v1.z += r1.z; v1.w += r1.w;
    }
    if (RELU) {
      v0.x = fmaxf(v0.x, 0.f); v0.y = fmaxf(v0.y, 0.f);
      v0.z = fmaxf(v0.z, 0.f); v0.w = fmaxf(v0.w, 0.f);
      v1.x = fmaxf(v1.x, 0.f); v1.y = fmaxf(v1.y, 0.f);
      v1.z = fmaxf(v1.z, 0.f); v1.w = fmaxf(v1.w, 0.f);
    }
    *(float4*)&C[(size_t)r * N + c0] = v0;
    *(float4*)&C[(size_t)r * N + c1] = v1;
  }
}

// ---------------- attention: one block per (q, b*h) ----------------
// qkv: [B*S, 1536] with cols [0,512)=Q, [512,1024)=K, [1024,1536)=V, each h*64+d
__global__ __launch_bounds__(256) void attn_kernel(
    const float* __restrict__ qkv, float* __restrict__ conc) {
  int q = blockIdx.x;
  int bh = blockIdx.y;
  int b = bh >> 3, h = bh & 7;
  int tid = threadIdx.x;
  __shared__ float qv[64];
  __shared__ float sc[1024];
  __shared__ float red[256];
  __shared__ float stat[2];
  const float* base = qkv + (size_t)b * S_ * QKV_N;
  if (tid < 64) qv[tid] = base[(size_t)q * QKV_N + h * 64 + tid];
  __syncthreads();
  int nk = q + 1;
  float lmax = -1e30f;
  for (int k = tid; k < nk; k += 256) {
    const float* kr = base + (size_t)k * QKV_N + 512 + h * 64;
    float s = 0.f;
#pragma unroll
    for (int d = 0; d < 64; d += 4) {
      float4 kv4 = *(const float4*)(kr + d);
      s += qv[d] * kv4.x + qv[d + 1] * kv4.y + qv[d + 2] * kv4.z + qv[d + 3] * kv4.w;
    }
    s *= 0.125f;  // 1/sqrt(64)
    sc[k] = s;
    lmax = fmaxf(lmax, s);
  }
  red[tid] = lmax;
  __syncthreads();
  for (int s = 128; s > 0; s >>= 1) {
    if (tid < s) red[tid] = fmaxf(red[tid], red[tid + s]);
    __syncthreads();
  }
  if (tid == 0) stat[0] = red[0];
  __syncthreads();
  float mx = stat[0];
  float lsum = 0.f;
  for (int k = tid; k < nk; k += 256) {
    float p = __expf(sc[k] - mx);
    sc[k] = p;
    lsum += p;
  }
  red[tid] = lsum;
  __syncthreads();
  for (int s = 128; s > 0; s >>= 1) {
    if (tid < s) red[tid] += red[tid + s];
    __syncthreads();
  }
  if (tid == 0) stat[1] = 1.f / red[0];
  __syncthreads();
  float inv = stat[1];
  int d = tid & 63, kc = tid >> 6;
  float acc = 0.f;
  for (int k = kc; k < nk; k += 4)
    acc += sc[k] * base[(size_t)k * QKV_N + 1024 + h * 64 + d];
  __syncthreads();
  red[tid] = acc;
  __syncthreads();
  if (tid < 64) {
    float r_ = red[d] + red[64 + d] + red[128 + d] + red[192 + d];
    conc[(size_t)(b * S_ + q) * (H_ * D_) + h * 64 + d] = r_ * inv;
  }
}

// ---------------- layernorm over E=512, one block per row ----------------
__global__ __launch_bounds__(256) void ln_kernel(
    const float* __restrict__ in, const float* __restrict__ g,
    const float* __restrict__ b, float* __restrict__ out) {
  __shared__ float red[256];
  __shared__ float stat[2];
  int row = blockIdx.x, tid = threadIdx.x;
  const float* r = in + (size_t)row * E_;
  float x0 = r[tid], x1 = r[tid + 256];
  red[tid] = x0 + x1;
  __syncthreads();
  for (int s = 128; s > 0; s >>= 1) {
    if (tid < s) red[tid] += red[tid + s];
    __syncthreads();
  }
  if (tid == 0) stat[0] = red[0] * (1.f / 512.f);
  __syncthreads();
  float mu = stat[0];
  float d0 = x0 - mu, d1 = x1 - mu;
  red[tid] = d0 * d0 + d1 * d1;
  __syncthreads();
  for (int s = 128; s > 0; s >>= 1) {
    if (tid < s) red[tid] += red[tid + s];
    __syncthreads();
  }
  if (tid == 0) stat[1] = rsqrtf(red[0] * (1.f / 512.f) + 1e-5f);
  __syncthreads();
  float rs = stat[1];
  out[(size_t)row * E_ + tid] = d0 * rs * g[tid] + b[tid];
  out[(size_t)row * E_ + tid + 256] = d1 * rs * g[tid + 256] + b[tid + 256];
}

// ---------------- host ----------------
extern "C" void kernel_launch(void* const* d_in, const int* in_sizes, int n_in,
                              void* d_out, int out_size, void* d_ws, size_t ws_size,
                              hipStream_t stream) {
  const int* x = (const int*)d_in[0];
  const float* tok = (const float*)d_in[1];
  const float* pos = (const float*)d_in[2];
  const float* Wq = (const float*)d_in[3];
  const float* bq = (const float*)d_in[4];
  const float* Wk = (const float*)d_in[5];
  const float* bk = (const float*)d_in[6];
  const float* Wv = (const float*)d_in[7];
  const float* bv = (const float*)d_in[8];
  const float* Wo = (const float*)d_in[9];
  const float* bo = (const float*)d_in[10];
  const float* W1 = (const float*)d_in[11];
  const float* b1 = (const float*)d_in[12];
  const float* W2 = (const float*)d_in[13];
  const float* b2 = (const float*)d_in[14];
  const float* ln1g = (const float*)d_in[15];
  const float* ln1b = (const float*)d_in[16];
  const float* ln2g = (const float*)d_in[17];
  const float* ln2b = (const float*)d_in[18];
  const float* Wout = (const float*)d_in[19];
  const float* bout = (const float*)d_in[20];
  float* out = (float*)d_out;

  float* ws = (float*)d_ws;
  float* hbuf  = ws;                       // 1,048,576
  float* qkvb  = hbuf + 1048576;           // 3,145,728
  float* concb = qkvb + 3145728;           // 1,048,576
  float* t1    = concb + 1048576;          // 1,048,576
  float* lnb   = t1 + 1048576;             // 1,048,576
  float* ffb   = lnb + 1048576;            // 4,194,304
  float* wpack = ffb + 4194304;            // 3,145,728
  float* bpack = wpack + 3145728;          // 6,144

  // pack weights/biases
  pack_w_kernel<<<(L_ * E_ * QKV_N) / 256, 256, 0, stream>>>(Wq, Wk, Wv, wpack);
  pack_b_kernel<<<(L_ * QKV_N + 255) / 256, 256, 0, stream>>>(bq, bk, bv, bpack);

  // embedding
  embed_kernel<<<(M_ * E_) / 256, 256, 0, stream>>>(x, tok, pos, hbuf);

  for (int l = 0; l < L_; ++l) {
    // QKV projection: [2048,512] @ [512,1536]
    gemm64_kernel<false><<<dim3(QKV_N / 64, M_ / 64), 256, 0, stream>>>(
        hbuf, wpack + (size_t)l * E_ * QKV_N, bpack + l * QKV_N, nullptr,
        qkvb, M_, QKV_N, E_);
    // attention
    attn_kernel<<<dim3(S_, B_ * H_), 256, 0, stream>>>(qkvb, concb);
    // output projection + residual: [2048,512] @ [512,512] + h
    gemm64_kernel<false><<<dim3(E_ / 64, M_ / 64), 256, 0, stream>>>(
        concb, Wo + (size_t)l * H_ * D_ * E_, bo + l * E_, hbuf, t1, M_, E_, H_ * D_);
    ln_kernel<<<M_, 256, 0, stream>>>(t1, ln1g + l * E_, ln1b + l * E_, lnb);
    // FF1 + ReLU: [2048,512] @ [512,2048]
    gemm128_kernel<true><<<dim3(FF_ / 128, M_ / 128), 256, 0, stream>>>(
        lnb, W1 + (size_t)l * E_ * FF_, b1 + l * FF_, nullptr, ffb, M_, FF_, E_);
    // FF2 + residual: [2048,2048] @ [2048,512] + ln
    gemm64_kernel<false><<<dim3(E_ / 64, M_ / 64), 256, 0, stream>>>(
        ffb, W2 + (size_t)l * FF_ * E_, b2 + l * E_, lnb, t1, M_, E_, FF_);
    ln_kernel<<<M_, 256, 0, stream>>>(t1, ln2g + l * E_, ln2b + l * E_, hbuf);
  }

  // final projection: [2048,512] @ [512,32000]
  gemm128_kernel<false><<<dim3(V_ / 128, M_ / 128), 256, 0, stream>>>(
      hbuf, Wout, bout, nullptr, out, M_, V_, E_);
}

// Round 2
// 2244.532 us; speedup vs baseline: 1.7062x; 1.7062x over previous
//
#include <hip/hip_runtime.h>
#include <hip/hip_bf16.h>

// GPT forward: B=2, S=1024, E=512, H=8, D=64, L=4, FF=2048, V=32000
// Round 2: bf16 MFMA GEMMs (m97 structure: 128^2 tile, BK=32, global_load_lds,
// B^T weight layout), fp32 residual stream + LN, bf16 activations as GEMM inputs.

#define B_ 2
#define S_ 1024
#define E_ 512
#define H_ 8
#define D_ 64
#define L_ 4
#define FF_ 2048
#define V_ 32000
#define M_ (B_ * S_)          // 2048 rows
#define QKV_N (3 * H_ * D_)   // 1536

typedef __attribute__((ext_vector_type(8))) short short8;
typedef __attribute__((ext_vector_type(4))) float f32x4;

__device__ __forceinline__ float b2f(ushort u) {
  union { uint32_t i; float f; } c; c.i = ((uint32_t)u) << 16; return c.f;
}
__device__ __forceinline__ ushort f2b(float f) {
  union { float f; uint32_t i; } c; c.f = f;
  uint32_t u = c.i;
  return (ushort)((u + 0x7FFFu + ((u >> 16) & 1u)) >> 16);
}

__device__ __forceinline__ void gload16(const ushort* g, ushort* l) {
  __builtin_amdgcn_global_load_lds(
      (const __attribute__((address_space(1))) void*)g,
      (__attribute__((address_space(3))) void*)l, 16, 0, 0);
}

// ---------------- embed: h = tok_emb[x] + pos_emb (fp32 + bf16 copies) -------
__global__ __launch_bounds__(256) void embed_kernel(
    const int* __restrict__ x, const float* __restrict__ tok,
    const float* __restrict__ pos, float* __restrict__ hf,
    ushort* __restrict__ hb) {
  int idx = blockIdx.x * 256 + threadIdx.x;  // over B*S*E
  int e = idx & (E_ - 1);
  int t = (idx >> 9) & (S_ - 1);
  int b = idx >> 19;
  int tokid = x[b * S_ + t];
  float v = tok[(size_t)tokid * E_ + e] + pos[(size_t)t * E_ + e];
  hf[idx] = v;
  hb[idx] = f2b(v);
}

// ------------- tiled transpose+convert: in fp32 [R][C] -> out bf16 [C][R] ----
// batched: bz -> (b1 = bz/B2, b2 = bz%B2); element strides.
__global__ __launch_bounds__(256) void transpose_cvt_kernel(
    const float* __restrict__ in, ushort* __restrict__ out, int R, int C,
    int B2, long long inS1, long long inS2, long long outS1, long long outS2) {
  __shared__ float tile[32][33];
  int bz = blockIdx.z;
  int b1 = bz / B2, b2 = bz % B2;
  in += (size_t)b1 * inS1 + (size_t)b2 * inS2;
  out += (size_t)b1 * outS1 + (size_t)b2 * outS2;
  int r0 = blockIdx.x * 32, c0 = blockIdx.y * 32;
  int tx = threadIdx.x & 31, ty = threadIdx.x >> 5;  // ty 0..7
#pragma unroll
  for (int i = 0; i < 4; i++)
    tile[ty + 8 * i][tx] = in[(size_t)(r0 + ty + 8 * i) * C + c0 + tx];
  __syncthreads();
#pragma unroll
  for (int i = 0; i < 4; i++)
    out[(size_t)(c0 + ty + 8 * i) * R + r0 + tx] = f2b(tile[tx][ty + 8 * i]);
}

// ---------------- pack QKV biases [L][H*D]*3 -> [L][1536] fp32 ---------------
__global__ __launch_bounds__(256) void pack_b_kernel(
    const float* __restrict__ bq, const float* __restrict__ bk,
    const float* __restrict__ bv, float* __restrict__ bp) {
  int idx = blockIdx.x * 256 + threadIdx.x;
  if (idx >= L_ * QKV_N) return;
  int n = idx % QKV_N;
  int l = idx / QKV_N;
  int t = n / (H_ * D_);
  int hd = n % (H_ * D_);
  const float* src = (t == 0) ? bq : (t == 1) ? bk : bv;
  bp[idx] = src[(size_t)l * H_ * D_ + hd];
}

// ---------------- MFMA GEMM: C[M,N] = A[M,K](bf16) @ Bt[N,K](bf16) -----------
// 128x128 tile, BK=32, 4 waves -> 64x64/wave, 16x16x32 MFMA, 4x4 frags.
template <bool OUTBF, bool RELU>
__global__ __launch_bounds__(256) void mfma_gemm_kernel(
    const ushort* __restrict__ A, const ushort* __restrict__ Bt,
    const float* __restrict__ bias, const float* __restrict__ resid,
    void* __restrict__ out, int M, int N, int K) {
  __shared__ __align__(16) ushort As[128 * 32];
  __shared__ __align__(16) ushort Bs[128 * 32];
  int tid = threadIdx.x;
  int w = tid >> 6, l = tid & 63;
  int wr = w >> 1, wc = w & 1;
  int lane15 = l & 15, lhi = l >> 4;
  int row0 = blockIdx.y * 128, col0 = blockIdx.x * 128;

  // staging: chunk c covers rows [c*16, c*16+16) x 32 k-elems; wave w does c=w, w+4
  int sr = l >> 2;           // row within chunk
  int sk = (l & 3) << 3;     // k offset (8 bf16 = 16B per lane)
  const ushort* ga0 = A + (size_t)(row0 + w * 16 + sr) * K + sk;
  const ushort* ga1 = A + (size_t)(row0 + (w + 4) * 16 + sr) * K + sk;
  const ushort* gb0 = Bt + (size_t)(col0 + w * 16 + sr) * K + sk;
  const ushort* gb1 = Bt + (size_t)(col0 + (w + 4) * 16 + sr) * K + sk;
  ushort* lA0 = &As[w * 512 + l * 8];
  ushort* lA1 = &As[(w + 4) * 512 + l * 8];
  ushort* lB0 = &Bs[w * 512 + l * 8];
  ushort* lB1 = &Bs[(w + 4) * 512 + l * 8];

  f32x4 acc[4][4] = {};

  for (int k0 = 0; k0 < K; k0 += 32) {
    gload16(ga0 + k0, lA0);
    gload16(ga1 + k0, lA1);
    gload16(gb0 + k0, lB0);
    gload16(gb1 + k0, lB1);
    __syncthreads();
    short8 a[4], b[4];
#pragma unroll
    for (int i = 0; i < 4; i++) {
      a[i] = *(const short8*)&As[(wr * 64 + i * 16 + lane15) * 32 + lhi * 8];
      b[i] = *(const short8*)&Bs[(wc * 64 + i * 16 + lane15) * 32 + lhi * 8];
    }
#pragma unroll
    for (int i = 0; i < 4; i++)
#pragma unroll
      for (int j = 0; j < 4; j++)
        acc[i][j] = __builtin_amdgcn_mfma_f32_16x16x32_bf16(a[i], b[j], acc[i][j], 0, 0, 0);
    __syncthreads();
  }

  float* outf = (float*)out;
  ushort* outb = (ushort*)out;
#pragma unroll
  for (int i = 0; i < 4; i++) {
    int gr = row0 + wr * 64 + i * 16 + lhi * 4;
#pragma unroll
    for (int j = 0; j < 4; j++) {
      int gc = col0 + wc * 64 + j * 16 + lane15;
      float bb = bias[gc];
#pragma unroll
      for (int r = 0; r < 4; r++) {
        float v = acc[i][j][r] + bb;
        if (resid) v += resid[(size_t)(gr + r) * N + gc];
        if (RELU) v = fmaxf(v, 0.f);
        if (OUTBF) outb[(size_t)(gr + r) * N + gc] = f2b(v);
        else outf[(size_t)(gr + r) * N + gc] = v;
      }
    }
  }
}

// ---------------- attention: one block per (q, b*h); bf16 in/out -------------
__device__ __forceinline__ float dot8(const float* qv, uint4 kv) {
  return qv[0] * b2f((ushort)(kv.x & 0xffff)) + qv[1] * b2f((ushort)(kv.x >> 16)) +
         qv[2] * b2f((ushort)(kv.y & 0xffff)) + qv[3] * b2f((ushort)(kv.y >> 16)) +
         qv[4] * b2f((ushort)(kv.z & 0xffff)) + qv[5] * b2f((ushort)(kv.z >> 16)) +
         qv[6] * b2f((ushort)(kv.w & 0xffff)) + qv[7] * b2f((ushort)(kv.w >> 16));
}

__global__ __launch_bounds__(256) void attn_kernel(
    const ushort* __restrict__ qkv, ushort* __restrict__ conc) {
  int q = blockIdx.x;
  int bh = blockIdx.y;
  int b = bh >> 3, h = bh & 7;
  int tid = threadIdx.x;
  __shared__ float qv[64];
  __shared__ float sc[1024];
  __shared__ float red[256];
  __shared__ float stat[2];
  const ushort* base = qkv + (size_t)b * S_ * QKV_N;
  if (tid < 64) qv[tid] = b2f(base[(size_t)q * QKV_N + h * 64 + tid]);
  __syncthreads();
  int nk = q + 1;
  float lmax = -1e30f;
  for (int k = tid; k < nk; k += 256) {
    const ushort* kr = base + (size_t)k * QKV_N + 512 + h * 64;
    float s = 0.f;
#pragma unroll
    for (int d = 0; d < 64; d += 8)
      s += dot8(&qv[d], *(const uint4*)(kr + d));
    s *= 0.125f;  // 1/sqrt(64)
    sc[k] = s;
    lmax = fmaxf(lmax, s);
  }
  red[tid] = lmax;
  __syncthreads();
  for (int s = 128; s > 0; s >>= 1) {
    if (tid < s) red[tid] = fmaxf(red[tid], red[tid + s]);
    __syncthreads();
  }
  if (tid == 0) stat[0] = red[0];
  __syncthreads();
  float mx = stat[0];
  float lsum = 0.f;
  for (int k = tid; k < nk; k += 256) {
    float p = __expf(sc[k] - mx);
    sc[k] = p;
    lsum += p;
  }
  red[tid] = lsum;
  __syncthreads();
  for (int s = 128; s > 0; s >>= 1) {
    if (tid < s) red[tid] += red[tid + s];
    __syncthreads();
  }
  if (tid == 0) stat[1] = 1.f / red[0];
  __syncthreads();
  float inv = stat[1];
  int d = tid & 63, kc = tid >> 6;
  float acc = 0.f;
  for (int k = kc; k < nk; k += 4)
    acc += sc[k] * b2f(base[(size_t)k * QKV_N + 1024 + h * 64 + d]);
  __syncthreads();
  red[tid] = acc;
  __syncthreads();
  if (tid < 64) {
    float r_ = red[d] + red[64 + d] + red[128 + d] + red[192 + d];
    conc[(size_t)(b * S_ + q) * (H_ * D_) + h * 64 + d] = f2b(r_ * inv);
  }
}

// ---------------- layernorm over E=512; fp32 in, fp32+bf16 out ---------------
__global__ __launch_bounds__(256) void ln_kernel(
    const float* __restrict__ in, const float* __restrict__ g,
    const float* __restrict__ b, float* __restrict__ outf,
    ushort* __restrict__ outb) {
  __shared__ float red[256];
  __shared__ float stat[2];
  int row = blockIdx.x, tid = threadIdx.x;
  const float* r = in + (size_t)row * E_;
  float x0 = r[tid], x1 = r[tid + 256];
  red[tid] = x0 + x1;
  __syncthreads();
  for (int s = 128; s > 0; s >>= 1) {
    if (tid < s) red[tid] += red[tid + s];
    __syncthreads();
  }
  if (tid == 0) stat[0] = red[0] * (1.f / 512.f);
  __syncthreads();
  float mu = stat[0];
  float d0 = x0 - mu, d1 = x1 - mu;
  red[tid] = d0 * d0 + d1 * d1;
  __syncthreads();
  for (int s = 128; s > 0; s >>= 1) {
    if (tid < s) red[tid] += red[tid + s];
    __syncthreads();
  }
  if (tid == 0) stat[1] = rsqrtf(red[0] * (1.f / 512.f) + 1e-5f);
  __syncthreads();
  float rs = stat[1];
  float y0 = d0 * rs * g[tid] + b[tid];
  float y1 = d1 * rs * g[tid + 256] + b[tid + 256];
  outf[(size_t)row * E_ + tid] = y0;
  outf[(size_t)row * E_ + tid + 256] = y1;
  outb[(size_t)row * E_ + tid] = f2b(y0);
  outb[(size_t)row * E_ + tid + 256] = f2b(y1);
}

// ---------------- host ----------------
extern "C" void kernel_launch(void* const* d_in, const int* in_sizes, int n_in,
                              void* d_out, int out_size, void* d_ws, size_t ws_size,
                              hipStream_t stream) {
  const int* x = (const int*)d_in[0];
  const float* tok = (const float*)d_in[1];
  const float* pos = (const float*)d_in[2];
  const float* Wq = (const float*)d_in[3];
  const float* bq = (const float*)d_in[4];
  const float* Wk = (const float*)d_in[5];
  const float* bk = (const float*)d_in[6];
  const float* Wv = (const float*)d_in[7];
  const float* bv = (const float*)d_in[8];
  const float* Wo = (const float*)d_in[9];
  const float* bo = (const float*)d_in[10];
  const float* W1 = (const float*)d_in[11];
  const float* b1 = (const float*)d_in[12];
  const float* W2 = (const float*)d_in[13];
  const float* b2 = (const float*)d_in[14];
  const float* ln1g = (const float*)d_in[15];
  const float* ln1b = (const float*)d_in[16];
  const float* ln2g = (const float*)d_in[17];
  const float* ln2b = (const float*)d_in[18];
  const float* Wout = (const float*)d_in[19];
  const float* bout = (const float*)d_in[20];
  float* out = (float*)d_out;

  char* p = (char*)d_ws;
  auto alloc = [&](size_t bytes) {
    char* r = p;
    p += (bytes + 255) & ~(size_t)255;
    return r;
  };
  float* h_f = (float*)alloc((size_t)M_ * E_ * 4);
  ushort* h_b = (ushort*)alloc((size_t)M_ * E_ * 2);
  ushort* qkv_b = (ushort*)alloc((size_t)M_ * QKV_N * 2);
  ushort* conc_b = (ushort*)alloc((size_t)M_ * E_ * 2);
  float* t_f = (float*)alloc((size_t)M_ * E_ * 4);
  float* ln_f = (float*)alloc((size_t)M_ * E_ * 4);
  ushort* ln_b = (ushort*)alloc((size_t)M_ * E_ * 2);
  ushort* ff_b = (ushort*)alloc((size_t)M_ * FF_ * 2);
  ushort* wqkv = (ushort*)alloc((size_t)L_ * QKV_N * E_ * 2);
  float* bqkv = (float*)alloc((size_t)L_ * QKV_N * 4);
  ushort* wo_t = (ushort*)alloc((size_t)L_ * E_ * E_ * 2);
  ushort* w1_t = (ushort*)alloc((size_t)L_ * FF_ * E_ * 2);
  ushort* w2_t = (ushort*)alloc((size_t)L_ * E_ * FF_ * 2);
  ushort* wout_t = (ushort*)alloc((size_t)V_ * E_ * 2);

  // ---- weight conversion (per-launch; ~115 MB traffic) ----
  // Wq/Wk/Wv [L][H][E][D] -> wqkv [L][n=t*512+h*64+d][E]
  const float* wsrc[3] = {Wq, Wk, Wv};
  for (int t = 0; t < 3; t++)
    transpose_cvt_kernel<<<dim3(E_ / 32, D_ / 32, L_ * H_), 256, 0, stream>>>(
        wsrc[t], wqkv + (size_t)t * 512 * E_, E_, D_, H_,
        (long long)H_ * E_ * D_, (long long)E_ * D_,
        (long long)QKV_N * E_, (long long)D_ * E_);
  // Wo [L][512][512] -> wo_t [L][512][512]^T
  transpose_cvt_kernel<<<dim3(16, 16, L_), 256, 0, stream>>>(
      Wo, wo_t, 512, 512, 1, (long long)512 * 512, 0, (long long)512 * 512, 0);
  // W1 [L][E][FF] -> w1_t [L][FF][E]
  transpose_cvt_kernel<<<dim3(E_ / 32, FF_ / 32, L_), 256, 0, stream>>>(
      W1, w1_t, E_, FF_, 1, (long long)E_ * FF_, 0, (long long)FF_ * E_, 0);
  // W2 [L][FF][E] -> w2_t [L][E][FF]
  transpose_cvt_kernel<<<dim3(FF_ / 32, E_ / 32, L_), 256, 0, stream>>>(
      W2, w2_t, FF_, E_, 1, (long long)FF_ * E_, 0, (long long)E_ * FF_, 0);
  // Wout [E][V] -> wout_t [V][E]
  transpose_cvt_kernel<<<dim3(E_ / 32, V_ / 32, 1), 256, 0, stream>>>(
      Wout, wout_t, E_, V_, 1, 0, 0, 0, 0);
  pack_b_kernel<<<(L_ * QKV_N + 255) / 256, 256, 0, stream>>>(bq, bk, bv, bqkv);

  // ---- embedding ----
  embed_kernel<<<(M_ * E_) / 256, 256, 0, stream>>>(x, tok, pos, h_f, h_b);

  for (int l = 0; l < L_; ++l) {
    // QKV: [2048,512] @ [512,1536] -> bf16
    mfma_gemm_kernel<true, false><<<dim3(QKV_N / 128, M_ / 128), 256, 0, stream>>>(
        h_b, wqkv + (size_t)l * QKV_N * E_, bqkv + l * QKV_N, nullptr,
        qkv_b, M_, QKV_N, E_);
    attn_kernel<<<dim3(S_, B_ * H_), 256, 0, stream>>>(qkv_b, conc_b);
    // Wo + residual(h_f): -> t_f fp32
    mfma_gemm_kernel<false, false><<<dim3(E_ / 128, M_ / 128), 256, 0, stream>>>(
        conc_b, wo_t + (size_t)l * E_ * E_, bo + l * E_, h_f, t_f, M_, E_, E_);
    ln_kernel<<<M_, 256, 0, stream>>>(t_f, ln1g + l * E_, ln1b + l * E_, ln_f, ln_b);
    // FF1 + ReLU: [2048,512] @ [512,2048] -> bf16
    mfma_gemm_kernel<true, true><<<dim3(FF_ / 128, M_ / 128), 256, 0, stream>>>(
        ln_b, w1_t + (size_t)l * FF_ * E_, b1 + l * FF_, nullptr, ff_b, M_, FF_, E_);
    // FF2 + residual(ln_f): [2048,2048] @ [2048,512] -> t_f fp32
    mfma_gemm_kernel<false, false><<<dim3(E_ / 128, M_ / 128), 256, 0, stream>>>(
        ff_b, w2_t + (size_t)l * E_ * FF_, b2 + l * E_, ln_f, t_f, M_, E_, FF_);
    ln_kernel<<<M_, 256, 0, stream>>>(t_f, ln2g + l * E_, ln2b + l * E_, h_f, h_b);
  }

  // final projection: [2048,512] @ [512,32000] -> fp32 logits
  mfma_gemm_kernel<false, false><<<dim3(V_ / 128, M_ / 128), 256, 0, stream>>>(
      h_b, wout_t, bout, nullptr, out, M_, V_, E_);
}

// Round 3
// 875.508 us; speedup vs baseline: 4.3741x; 2.5637x over previous
//
#include <hip/hip_runtime.h>
#include <hip/hip_bf16.h>

// GPT forward: B=2, S=1024, E=512, H=8, D=64, L=4, FF=2048, V=32000
// Round 3: MFMA flash attention (16x16x32 bf16, online softmax, V^T buffer),
// bf16 MFMA GEMMs (m97 structure), fp32 residual stream + LN.

#define B_ 2
#define S_ 1024
#define E_ 512
#define H_ 8
#define D_ 64
#define L_ 4
#define FF_ 2048
#define V_ 32000
#define M_ (B_ * S_)          // 2048 rows
#define QKV_N (3 * H_ * D_)   // 1536

typedef __attribute__((ext_vector_type(8))) short short8;
typedef __attribute__((ext_vector_type(4))) float f32x4;

__device__ __forceinline__ float b2f(ushort u) {
  union { uint32_t i; float f; } c; c.i = ((uint32_t)u) << 16; return c.f;
}
__device__ __forceinline__ ushort f2b(float f) {
  union { float f; uint32_t i; } c; c.f = f;
  uint32_t u = c.i;
  return (ushort)((u + 0x7FFFu + ((u >> 16) & 1u)) >> 16);
}

__device__ __forceinline__ void gload16(const ushort* g, ushort* l) {
  __builtin_amdgcn_global_load_lds(
      (const __attribute__((address_space(1))) void*)g,
      (__attribute__((address_space(3))) void*)l, 16, 0, 0);
}

// ---------------- embed: h = tok_emb[x] + pos_emb (fp32 + bf16 copies) -------
__global__ __launch_bounds__(256) void embed_kernel(
    const int* __restrict__ x, const float* __restrict__ tok,
    const float* __restrict__ pos, float* __restrict__ hf,
    ushort* __restrict__ hb) {
  int idx = blockIdx.x * 256 + threadIdx.x;  // over B*S*E
  int e = idx & (E_ - 1);
  int t = (idx >> 9) & (S_ - 1);
  int b = idx >> 19;
  int tokid = x[b * S_ + t];
  float v = tok[(size_t)tokid * E_ + e] + pos[(size_t)t * E_ + e];
  hf[idx] = v;
  hb[idx] = f2b(v);
}

// ------------- tiled transpose+convert: in fp32 [R][C] -> out bf16 [C][R] ----
__global__ __launch_bounds__(256) void transpose_cvt_kernel(
    const float* __restrict__ in, ushort* __restrict__ out, int R, int C,
    int B2, long long inS1, long long inS2, long long outS1, long long outS2) {
  __shared__ float tile[32][33];
  int bz = blockIdx.z;
  int b1 = bz / B2, b2 = bz % B2;
  in += (size_t)b1 * inS1 + (size_t)b2 * inS2;
  out += (size_t)b1 * outS1 + (size_t)b2 * outS2;
  int r0 = blockIdx.x * 32, c0 = blockIdx.y * 32;
  int tx = threadIdx.x & 31, ty = threadIdx.x >> 5;  // ty 0..7
#pragma unroll
  for (int i = 0; i < 4; i++)
    tile[ty + 8 * i][tx] = in[(size_t)(r0 + ty + 8 * i) * C + c0 + tx];
  __syncthreads();
#pragma unroll
  for (int i = 0; i < 4; i++)
    out[(size_t)(c0 + ty + 8 * i) * R + r0 + tx] = f2b(tile[tx][ty + 8 * i]);
}

// ---------------- pack QKV biases [L][H*D]*3 -> [L][1536] fp32 ---------------
__global__ __launch_bounds__(256) void pack_b_kernel(
    const float* __restrict__ bq, const float* __restrict__ bk,
    const float* __restrict__ bv, float* __restrict__ bp) {
  int idx = blockIdx.x * 256 + threadIdx.x;
  if (idx >= L_ * QKV_N) return;
  int n = idx % QKV_N;
  int l = idx / QKV_N;
  int t = n / (H_ * D_);
  int hd = n % (H_ * D_);
  const float* src = (t == 0) ? bq : (t == 1) ? bk : bv;
  bp[idx] = src[(size_t)l * H_ * D_ + hd];
}

// ---------------- MFMA GEMM: C[M,N] = A[M,K](bf16) @ Bt[N,K](bf16) -----------
// 128x128 tile, BK=32, 4 waves -> 64x64/wave, 16x16x32 MFMA, 4x4 frags.
template <bool OUTBF, bool RELU>
__global__ __launch_bounds__(256) void mfma_gemm_kernel(
    const ushort* __restrict__ A, const ushort* __restrict__ Bt,
    const float* __restrict__ bias, const float* __restrict__ resid,
    void* __restrict__ out, int M, int N, int K) {
  __shared__ __align__(16) ushort As[128 * 32];
  __shared__ __align__(16) ushort Bs[128 * 32];
  int tid = threadIdx.x;
  int w = tid >> 6, l = tid & 63;
  int wr = w >> 1, wc = w & 1;
  int lane15 = l & 15, lhi = l >> 4;
  int row0 = blockIdx.y * 128, col0 = blockIdx.x * 128;

  int sr = l >> 2;           // row within chunk
  int sk = (l & 3) << 3;     // k offset (8 bf16 = 16B per lane)
  const ushort* ga0 = A + (size_t)(row0 + w * 16 + sr) * K + sk;
  const ushort* ga1 = A + (size_t)(row0 + (w + 4) * 16 + sr) * K + sk;
  const ushort* gb0 = Bt + (size_t)(col0 + w * 16 + sr) * K + sk;
  const ushort* gb1 = Bt + (size_t)(col0 + (w + 4) * 16 + sr) * K + sk;
  ushort* lA0 = &As[w * 512 + l * 8];
  ushort* lA1 = &As[(w + 4) * 512 + l * 8];
  ushort* lB0 = &Bs[w * 512 + l * 8];
  ushort* lB1 = &Bs[(w + 4) * 512 + l * 8];

  f32x4 acc[4][4] = {};

  for (int k0 = 0; k0 < K; k0 += 32) {
    gload16(ga0 + k0, lA0);
    gload16(ga1 + k0, lA1);
    gload16(gb0 + k0, lB0);
    gload16(gb1 + k0, lB1);
    __syncthreads();
    short8 a[4], b[4];
#pragma unroll
    for (int i = 0; i < 4; i++) {
      a[i] = *(const short8*)&As[(wr * 64 + i * 16 + lane15) * 32 + lhi * 8];
      b[i] = *(const short8*)&Bs[(wc * 64 + i * 16 + lane15) * 32 + lhi * 8];
    }
#pragma unroll
    for (int i = 0; i < 4; i++)
#pragma unroll
      for (int j = 0; j < 4; j++)
        acc[i][j] = __builtin_amdgcn_mfma_f32_16x16x32_bf16(a[i], b[j], acc[i][j], 0, 0, 0);
    __syncthreads();
  }

  float* outf = (float*)out;
  ushort* outb = (ushort*)out;
#pragma unroll
  for (int i = 0; i < 4; i++) {
    int gr = row0 + wr * 64 + i * 16 + lhi * 4;
#pragma unroll
    for (int j = 0; j < 4; j++) {
      int gc = col0 + wc * 64 + j * 16 + lane15;
      float bb = bias[gc];
#pragma unroll
      for (int r = 0; r < 4; r++) {
        float v = acc[i][j][r] + bb;
        if (resid) v += resid[(size_t)(gr + r) * N + gc];
        if (RELU) v = fmaxf(v, 0.f);
        if (OUTBF) outb[(size_t)(gr + r) * N + gc] = f2b(v);
        else outf[(size_t)(gr + r) * N + gc] = v;
      }
    }
  }
}

// -------- bf16 transpose of V: qkv[b][s][1024+h*64+d] -> vt[b*8+h][d][s] -----
__global__ __launch_bounds__(256) void vtrans_kernel(
    const ushort* __restrict__ qkv, ushort* __restrict__ vt) {
  __shared__ ushort tile[32][36];
  int s0 = blockIdx.x * 32;
  int d0 = blockIdx.y * 32;
  int bh = blockIdx.z;
  int b = bh >> 3, h = bh & 7;
  int tx = threadIdx.x & 7, ty = threadIdx.x >> 3;  // tx 0..7, ty 0..31
  // load 32 s-rows x 32 d-cols (ushort4 per thread)
  const ushort* src = qkv + (size_t)(b * S_ + s0 + ty) * QKV_N + 1024 + h * 64 + d0 + tx * 4;
  ushort4 v = *(const ushort4*)src;
  tile[tx * 4 + 0][ty] = v.x;
  tile[tx * 4 + 1][ty] = v.y;
  tile[tx * 4 + 2][ty] = v.z;
  tile[tx * 4 + 3][ty] = v.w;
  __syncthreads();
  // write rows of vt: d = d0+ty, s = s0 + tx*4..+3
  ushort4 o;
  o.x = tile[ty][tx * 4 + 0];
  o.y = tile[ty][tx * 4 + 1];
  o.z = tile[ty][tx * 4 + 2];
  o.w = tile[ty][tx * 4 + 3];
  *(ushort4*)(vt + ((size_t)bh * 64 + d0 + ty) * S_ + s0 + tx * 4) = o;
}

// ---------------- MFMA flash attention ----------------
// grid (S/64, B*H), 256 threads = 4 waves; wave w owns 16 q-rows q0 = qb*64+w*16.
// Q,K read from qkv (bf16), V from vt [bh][64][1024]. Causal, online softmax.
__global__ __launch_bounds__(256) void fattn_kernel(
    const ushort* __restrict__ qkv, const ushort* __restrict__ vt,
    ushort* __restrict__ conc) {
  int qb = blockIdx.x;
  int bh = blockIdx.y;
  int b = bh >> 3, h = bh & 7;
  int w = threadIdx.x >> 6, l = threadIdx.x & 63;
  int lane15 = l & 15, lhi = l >> 4;
  int q0 = qb * 64 + w * 16;

  __shared__ __align__(16) ushort plds[4][16][40];  // per-wave P tile, 80B rows

  // Q fragments (16 rows x 64 D, two 32-wide K chunks)
  const ushort* qr = qkv + (size_t)(b * S_ + q0 + lane15) * QKV_N + h * 64;
  short8 qf0 = *(const short8*)(qr + lhi * 8);
  short8 qf1 = *(const short8*)(qr + 32 + lhi * 8);

  f32x4 o[4] = {};           // 4 d-tiles of 16
  float m[4], lsum[4];
#pragma unroll
  for (int r = 0; r < 4; r++) { m[r] = -1e30f; lsum[r] = 0.f; }

  const ushort* vbase = vt + (size_t)bh * 64 * S_;
  int kv_end = q0 + 16;
  for (int kv0 = 0; kv0 < kv_end; kv0 += 32) {
    // QK^T: two 16x16 score tiles (kv cols 0-15, 16-31)
    f32x4 s[2] = {};
#pragma unroll
    for (int t = 0; t < 2; t++) {
      const ushort* kr = qkv + (size_t)(b * S_ + kv0 + t * 16 + lane15) * QKV_N + 512 + h * 64;
      short8 kf0 = *(const short8*)(kr + lhi * 8);
      short8 kf1 = *(const short8*)(kr + 32 + lhi * 8);
      s[t] = __builtin_amdgcn_mfma_f32_16x16x32_bf16(qf0, kf0, s[t], 0, 0, 0);
      s[t] = __builtin_amdgcn_mfma_f32_16x16x32_bf16(qf1, kf1, s[t], 0, 0, 0);
    }
    // scale + causal mask; row stats
    float sv[2][4];
    float rm[4];
#pragma unroll
    for (int r = 0; r < 4; r++) {
      int qidx = q0 + lhi * 4 + r;
#pragma unroll
      for (int t = 0; t < 2; t++) {
        float v = s[t][r] * 0.125f;
        int kidx = kv0 + t * 16 + lane15;
        if (kidx > qidx) v = -1e30f;
        sv[t][r] = v;
      }
      rm[r] = fmaxf(sv[0][r], sv[1][r]);
      rm[r] = fmaxf(rm[r], __shfl_xor(rm[r], 1));
      rm[r] = fmaxf(rm[r], __shfl_xor(rm[r], 2));
      rm[r] = fmaxf(rm[r], __shfl_xor(rm[r], 4));
      rm[r] = fmaxf(rm[r], __shfl_xor(rm[r], 8));
    }
    float sc[4];
#pragma unroll
    for (int r = 0; r < 4; r++) {
      float mn = fmaxf(m[r], rm[r]);
      sc[r] = __expf(m[r] - mn);
      m[r] = mn;
    }
    // p = exp(s - m), row sums, rescale O and l
#pragma unroll
    for (int r = 0; r < 4; r++) {
      float p0 = __expf(sv[0][r] - m[r]);
      float p1 = __expf(sv[1][r] - m[r]);
      plds[w][lhi * 4 + r][lane15] = f2b(p0);
      plds[w][lhi * 4 + r][16 + lane15] = f2b(p1);
      float rs = p0 + p1;
      rs += __shfl_xor(rs, 1);
      rs += __shfl_xor(rs, 2);
      rs += __shfl_xor(rs, 4);
      rs += __shfl_xor(rs, 8);
      lsum[r] = lsum[r] * sc[r] + rs;
#pragma unroll
      for (int n = 0; n < 4; n++) o[n][r] *= sc[r];
    }
    // P fragment (A operand, K=32) and PV
    short8 pa = *(const short8*)&plds[w][lane15][lhi * 8];
#pragma unroll
    for (int n = 0; n < 4; n++) {
      short8 vf = *(const short8*)(vbase + (size_t)(n * 16 + lane15) * S_ + kv0 + lhi * 8);
      o[n] = __builtin_amdgcn_mfma_f32_16x16x32_bf16(pa, vf, o[n], 0, 0, 0);
    }
  }
  // epilogue
#pragma unroll
  for (int r = 0; r < 4; r++) {
    float inv = 1.f / lsum[r];
    int row = b * S_ + q0 + lhi * 4 + r;
#pragma unroll
    for (int n = 0; n < 4; n++)
      conc[(size_t)row * (H_ * D_) + h * 64 + n * 16 + lane15] = f2b(o[n][r] * inv);
  }
}

// ---------------- layernorm over E=512; fp32 in, fp32+bf16 out ---------------
__global__ __launch_bounds__(256) void ln_kernel(
    const float* __restrict__ in, const float* __restrict__ g,
    const float* __restrict__ b, float* __restrict__ outf,
    ushort* __restrict__ outb) {
  __shared__ float red[256];
  __shared__ float stat[2];
  int row = blockIdx.x, tid = threadIdx.x;
  const float* r = in + (size_t)row * E_;
  float x0 = r[tid], x1 = r[tid + 256];
  red[tid] = x0 + x1;
  __syncthreads();
  for (int s = 128; s > 0; s >>= 1) {
    if (tid < s) red[tid] += red[tid + s];
    __syncthreads();
  }
  if (tid == 0) stat[0] = red[0] * (1.f / 512.f);
  __syncthreads();
  float mu = stat[0];
  float d0 = x0 - mu, d1 = x1 - mu;
  red[tid] = d0 * d0 + d1 * d1;
  __syncthreads();
  for (int s = 128; s > 0; s >>= 1) {
    if (tid < s) red[tid] += red[tid + s];
    __syncthreads();
  }
  if (tid == 0) stat[1] = rsqrtf(red[0] * (1.f / 512.f) + 1e-5f);
  __syncthreads();
  float rs = stat[1];
  float y0 = d0 * rs * g[tid] + b[tid];
  float y1 = d1 * rs * g[tid + 256] + b[tid + 256];
  outf[(size_t)row * E_ + tid] = y0;
  outf[(size_t)row * E_ + tid + 256] = y1;
  outb[(size_t)row * E_ + tid] = f2b(y0);
  outb[(size_t)row * E_ + tid + 256] = f2b(y1);
}

// ---------------- host ----------------
extern "C" void kernel_launch(void* const* d_in, const int* in_sizes, int n_in,
                              void* d_out, int out_size, void* d_ws, size_t ws_size,
                              hipStream_t stream) {
  const int* x = (const int*)d_in[0];
  const float* tok = (const float*)d_in[1];
  const float* pos = (const float*)d_in[2];
  const float* Wq = (const float*)d_in[3];
  const float* bq = (const float*)d_in[4];
  const float* Wk = (const float*)d_in[5];
  const float* bk = (const float*)d_in[6];
  const float* Wv = (const float*)d_in[7];
  const float* bv = (const float*)d_in[8];
  const float* Wo = (const float*)d_in[9];
  const float* bo = (const float*)d_in[10];
  const float* W1 = (const float*)d_in[11];
  const float* b1 = (const float*)d_in[12];
  const float* W2 = (const float*)d_in[13];
  const float* b2 = (const float*)d_in[14];
  const float* ln1g = (const float*)d_in[15];
  const float* ln1b = (const float*)d_in[16];
  const float* ln2g = (const float*)d_in[17];
  const float* ln2b = (const float*)d_in[18];
  const float* Wout = (const float*)d_in[19];
  const float* bout = (const float*)d_in[20];
  float* out = (float*)d_out;

  char* p = (char*)d_ws;
  auto alloc = [&](size_t bytes) {
    char* r = p;
    p += (bytes + 255) & ~(size_t)255;
    return r;
  };
  float* h_f = (float*)alloc((size_t)M_ * E_ * 4);
  ushort* h_b = (ushort*)alloc((size_t)M_ * E_ * 2);
  ushort* qkv_b = (ushort*)alloc((size_t)M_ * QKV_N * 2);
  ushort* conc_b = (ushort*)alloc((size_t)M_ * E_ * 2);
  float* t_f = (float*)alloc((size_t)M_ * E_ * 4);
  float* ln_f = (float*)alloc((size_t)M_ * E_ * 4);
  ushort* ln_b = (ushort*)alloc((size_t)M_ * E_ * 2);
  ushort* ff_b = (ushort*)alloc((size_t)M_ * FF_ * 2);
  ushort* vt_b = (ushort*)alloc((size_t)B_ * H_ * D_ * S_ * 2);
  ushort* wqkv = (ushort*)alloc((size_t)L_ * QKV_N * E_ * 2);
  float* bqkv = (float*)alloc((size_t)L_ * QKV_N * 4);
  ushort* wo_t = (ushort*)alloc((size_t)L_ * E_ * E_ * 2);
  ushort* w1_t = (ushort*)alloc((size_t)L_ * FF_ * E_ * 2);
  ushort* w2_t = (ushort*)alloc((size_t)L_ * E_ * FF_ * 2);
  ushort* wout_t = (ushort*)alloc((size_t)V_ * E_ * 2);

  // ---- weight conversion ----
  const float* wsrc[3] = {Wq, Wk, Wv};
  for (int t = 0; t < 3; t++)
    transpose_cvt_kernel<<<dim3(E_ / 32, D_ / 32, L_ * H_), 256, 0, stream>>>(
        wsrc[t], wqkv + (size_t)t * 512 * E_, E_, D_, H_,
        (long long)H_ * E_ * D_, (long long)E_ * D_,
        (long long)QKV_N * E_, (long long)D_ * E_);
  transpose_cvt_kernel<<<dim3(16, 16, L_), 256, 0, stream>>>(
      Wo, wo_t, 512, 512, 1, (long long)512 * 512, 0, (long long)512 * 512, 0);
  transpose_cvt_kernel<<<dim3(E_ / 32, FF_ / 32, L_), 256, 0, stream>>>(
      W1, w1_t, E_, FF_, 1, (long long)E_ * FF_, 0, (long long)FF_ * E_, 0);
  transpose_cvt_kernel<<<dim3(FF_ / 32, E_ / 32, L_), 256, 0, stream>>>(
      W2, w2_t, FF_, E_, 1, (long long)FF_ * E_, 0, (long long)E_ * FF_, 0);
  transpose_cvt_kernel<<<dim3(E_ / 32, V_ / 32, 1), 256, 0, stream>>>(
      Wout, wout_t, E_, V_, 1, 0, 0, 0, 0);
  pack_b_kernel<<<(L_ * QKV_N + 255) / 256, 256, 0, stream>>>(bq, bk, bv, bqkv);

  // ---- embedding ----
  embed_kernel<<<(M_ * E_) / 256, 256, 0, stream>>>(x, tok, pos, h_f, h_b);

  for (int l = 0; l < L_; ++l) {
    // QKV: [2048,512] @ [512,1536] -> bf16
    mfma_gemm_kernel<true, false><<<dim3(QKV_N / 128, M_ / 128), 256, 0, stream>>>(
        h_b, wqkv + (size_t)l * QKV_N * E_, bqkv + l * QKV_N, nullptr,
        qkv_b, M_, QKV_N, E_);
    // V transpose for PV B-operand
    vtrans_kernel<<<dim3(S_ / 32, D_ / 32, B_ * H_), 256, 0, stream>>>(qkv_b, vt_b);
    // flash attention
    fattn_kernel<<<dim3(S_ / 64, B_ * H_), 256, 0, stream>>>(qkv_b, vt_b, conc_b);
    // Wo + residual(h_f): -> t_f fp32
    mfma_gemm_kernel<false, false><<<dim3(E_ / 128, M_ / 128), 256, 0, stream>>>(
        conc_b, wo_t + (size_t)l * E_ * E_, bo + l * E_, h_f, t_f, M_, E_, E_);
    ln_kernel<<<M_, 256, 0, stream>>>(t_f, ln1g + l * E_, ln1b + l * E_, ln_f, ln_b);
    // FF1 + ReLU: [2048,512] @ [512,2048] -> bf16
    mfma_gemm_kernel<true, true><<<dim3(FF_ / 128, M_ / 128), 256, 0, stream>>>(
        ln_b, w1_t + (size_t)l * FF_ * E_, b1 + l * FF_, nullptr, ff_b, M_, FF_, E_);
    // FF2 + residual(ln_f): [2048,2048] @ [2048,512] -> t_f fp32
    mfma_gemm_kernel<false, false><<<dim3(E_ / 128, M_ / 128), 256, 0, stream>>>(
        ff_b, w2_t + (size_t)l * E_ * FF_, b2 + l * E_, ln_f, t_f, M_, E_, FF_);
    ln_kernel<<<M_, 256, 0, stream>>>(t_f, ln2g + l * E_, ln2b + l * E_, h_f, h_b);
  }

  // final projection: [2048,512] @ [512,32000] -> fp32 logits
  mfma_gemm_kernel<false, false><<<dim3(V_ / 128, M_ / 128), 256, 0, stream>>>(
      h_b, wout_t, bout, nullptr, out, M_, V_, E_);
}

// Round 4
// 851.420 us; speedup vs baseline: 4.4979x; 1.0283x over previous
//
#include <hip/hip_runtime.h>
#include <hip/hip_bf16.h>

// GPT forward: B=2, S=1024, E=512, H=8, D=64, L=4, FF=2048, V=32000
// Round 4: BK=64 swizzled-LDS MFMA GEMM + XCD swizzle on final GEMM,
// KVBLK=64 2-wave flash attention, fused V-transpose, 1-pass wave LN.

#define B_ 2
#define S_ 1024
#define E_ 512
#define H_ 8
#define D_ 64
#define L_ 4
#define FF_ 2048
#define V_ 32000
#define M_ (B_ * S_)          // 2048 rows
#define QKV_N (3 * H_ * D_)   // 1536

typedef __attribute__((ext_vector_type(8))) short short8;
typedef __attribute__((ext_vector_type(4))) float f32x4;

__device__ __forceinline__ float b2f(ushort u) {
  union { uint32_t i; float f; } c; c.i = ((uint32_t)u) << 16; return c.f;
}
__device__ __forceinline__ ushort f2b(float f) {
  union { float f; uint32_t i; } c; c.f = f;
  uint32_t u = c.i;
  return (ushort)((u + 0x7FFFu + ((u >> 16) & 1u)) >> 16);
}

__device__ __forceinline__ void gload16(const ushort* g, ushort* l) {
  __builtin_amdgcn_global_load_lds(
      (const __attribute__((address_space(1))) void*)g,
      (__attribute__((address_space(3))) void*)l, 16, 0, 0);
}

// ---------------- embed: h = tok_emb[x] + pos_emb (fp32 + bf16) --------------
__global__ __launch_bounds__(256) void embed_kernel(
    const int* __restrict__ x, const float* __restrict__ tok,
    const float* __restrict__ pos, float* __restrict__ hf,
    ushort* __restrict__ hb) {
  int idx = blockIdx.x * 256 + threadIdx.x;
  int e = idx & (E_ - 1);
  int t = (idx >> 9) & (S_ - 1);
  int b = idx >> 19;
  int tokid = x[b * S_ + t];
  float v = tok[(size_t)tokid * E_ + e] + pos[(size_t)t * E_ + e];
  hf[idx] = v;
  hb[idx] = f2b(v);
}

// ------------- generic tiled transpose+convert fp32 [R][C] -> bf16 [C][R] ----
__global__ __launch_bounds__(256) void transpose_cvt_kernel(
    const float* __restrict__ in, ushort* __restrict__ out, int R, int C,
    int B2, long long inS1, long long inS2, long long outS1, long long outS2) {
  __shared__ float tile[32][33];
  int bz = blockIdx.z;
  int b1 = bz / B2, b2 = bz % B2;
  in += (size_t)b1 * inS1 + (size_t)b2 * inS2;
  out += (size_t)b1 * outS1 + (size_t)b2 * outS2;
  int r0 = blockIdx.x * 32, c0 = blockIdx.y * 32;
  int tx = threadIdx.x & 31, ty = threadIdx.x >> 5;
#pragma unroll
  for (int i = 0; i < 4; i++)
    tile[ty + 8 * i][tx] = in[(size_t)(r0 + ty + 8 * i) * C + c0 + tx];
  __syncthreads();
#pragma unroll
  for (int i = 0; i < 4; i++)
    out[(size_t)(c0 + ty + 8 * i) * R + r0 + tx] = f2b(tile[tx][ty + 8 * i]);
}

// ------------- QKV weights [3][L][H][E][D] -> wqkv [L][t*512+h*64+d][E] ------
__global__ __launch_bounds__(256) void qkvw_kernel(
    const float* __restrict__ Wq, const float* __restrict__ Wk,
    const float* __restrict__ Wv, ushort* __restrict__ wqkv) {
  __shared__ float tile[32][33];
  int bz = blockIdx.z;            // 0..3*L*H-1
  int t = bz / (L_ * H_);
  int rem = bz % (L_ * H_);
  int lyr = rem / H_, h = rem % H_;
  const float* in = ((t == 0) ? Wq : (t == 1) ? Wk : Wv) +
                    ((size_t)lyr * H_ + h) * E_ * D_;
  ushort* out = wqkv + (size_t)lyr * QKV_N * E_ + ((size_t)t * 512 + h * 64) * E_;
  int r0 = blockIdx.x * 32, c0 = blockIdx.y * 32;  // r over E, c over D
  int tx = threadIdx.x & 31, ty = threadIdx.x >> 5;
#pragma unroll
  for (int i = 0; i < 4; i++)
    tile[ty + 8 * i][tx] = in[(size_t)(r0 + ty + 8 * i) * D_ + c0 + tx];
  __syncthreads();
#pragma unroll
  for (int i = 0; i < 4; i++)
    out[(size_t)(c0 + ty + 8 * i) * E_ + r0 + tx] = f2b(tile[tx][ty + 8 * i]);
}

// ---------------- pack QKV biases -> [L][1536] fp32 --------------------------
__global__ __launch_bounds__(256) void pack_b_kernel(
    const float* __restrict__ bq, const float* __restrict__ bk,
    const float* __restrict__ bv, float* __restrict__ bp) {
  int idx = blockIdx.x * 256 + threadIdx.x;
  if (idx >= L_ * QKV_N) return;
  int n = idx % QKV_N;
  int l = idx / QKV_N;
  int t = n / (H_ * D_);
  int hd = n % (H_ * D_);
  const float* src = (t == 0) ? bq : (t == 1) ? bk : bv;
  bp[idx] = src[(size_t)l * H_ * D_ + hd];
}

// ---------------- MFMA GEMM: C[M,N] = A[M,K](bf16) @ Bt[N,K](bf16) -----------
// 128x128 tile, BK=64, 4 waves -> 64x64/wave. XOR-swizzled LDS (pre-swizzled
// global source + swizzled ds_read; global_load_lds dest stays linear).
template <bool OUTBF, bool RELU, bool VT, bool SWZ>
__global__ __launch_bounds__(256) void mfma_gemm_kernel(
    const ushort* __restrict__ A, const ushort* __restrict__ Bt,
    const float* __restrict__ bias, const float* __restrict__ resid,
    void* __restrict__ out, ushort* __restrict__ vt,
    int M, int N, int K, int gx) {
  __shared__ __align__(16) ushort As[128 * 64];
  __shared__ __align__(16) ushort Bs[128 * 64];
  int tid = threadIdx.x;
  int w = tid >> 6, l = tid & 63;
  int wr = w >> 1, wc = w & 1;
  int lane15 = l & 15, lhi = l >> 4;

  int bid = blockIdx.x;
  int bx, by;
  if (SWZ) {
    // bijective XCD chunking (nwg % 8 == 0) + column-major decode: the 16
    // row-blocks sharing one B-panel run consecutively on one XCD.
    int nwg = gx * (M >> 7);
    int wg = (bid & 7) * (nwg >> 3) + (bid >> 3);
    by = wg & ((M >> 7) - 1);   // M/128 = 16 (pow2)
    bx = wg >> 4;
  } else {
    bx = bid % gx;
    by = bid / gx;
  }
  int row0 = by * 128, col0 = bx * 128;

  // staging: 8 chunks of 16 rows x 64 k per matrix; wave w does chunks w, w+4.
  // lane l in chunk c, half h: row = c*16 + h*8 + (l>>3), LDS byte = linear,
  // global k pre-swizzled so that swizzled ds_read sees the right element.
  int rr8 = l >> 3;
  int ksrc = (((l & 7) ^ rr8) << 3);          // k-elem offset (XOR bit4 of bytes)
  const ushort *gA[2][2], *gB[2][2];
  ushort *lA[2][2], *lB[2][2];
#pragma unroll
  for (int cc = 0; cc < 2; cc++) {
    int c = w + cc * 4;
#pragma unroll
    for (int h = 0; h < 2; h++) {
      int row = c * 16 + h * 8 + rr8;
      gA[cc][h] = A + (size_t)(row0 + row) * K + ksrc;
      gB[cc][h] = Bt + (size_t)(col0 + row) * K + ksrc;
      int ldst = c * 1024 + h * 512 + l * 8;  // ushort index, linear
      lA[cc][h] = &As[ldst];
      lB[cc][h] = &Bs[ldst];
    }
  }

  f32x4 acc[4][4] = {};

  for (int k0 = 0; k0 < K; k0 += 64) {
#pragma unroll
    for (int cc = 0; cc < 2; cc++)
#pragma unroll
      for (int h = 0; h < 2; h++) {
        gload16(gA[cc][h] + k0, lA[cc][h]);
        gload16(gB[cc][h] + k0, lB[cc][h]);
      }
    __syncthreads();
    short8 a[4][2], b[4][2];
    int sa = (lane15 & 7) << 4;                 // row&7 swizzle (bytes)
#pragma unroll
    for (int i = 0; i < 4; i++) {
      int ra = (wr * 64 + i * 16 + lane15) * 64;
      int rb = (wc * 64 + i * 16 + lane15) * 64;
#pragma unroll
      for (int kk = 0; kk < 2; kk++) {
        int inner = ((kk * 64 + lhi * 16) ^ sa) >> 1;  // ushort index
        a[i][kk] = *(const short8*)&As[ra + inner];
        b[i][kk] = *(const short8*)&Bs[rb + inner];
      }
    }
#pragma unroll
    for (int i = 0; i < 4; i++)
#pragma unroll
      for (int j = 0; j < 4; j++) {
        acc[i][j] = __builtin_amdgcn_mfma_f32_16x16x32_bf16(a[i][0], b[j][0], acc[i][j], 0, 0, 0);
        acc[i][j] = __builtin_amdgcn_mfma_f32_16x16x32_bf16(a[i][1], b[j][1], acc[i][j], 0, 0, 0);
      }
    __syncthreads();
  }

  float* outf = (float*)out;
  ushort* outb = (ushort*)out;
#pragma unroll
  for (int i = 0; i < 4; i++) {
    int gr = row0 + wr * 64 + i * 16 + lhi * 4;
#pragma unroll
    for (int j = 0; j < 4; j++) {
      int gc = col0 + wc * 64 + j * 16 + lane15;
      float bb = bias[gc];
#pragma unroll
      for (int r = 0; r < 4; r++) {
        float v = acc[i][j][r] + bb;
        if (resid) v += resid[(size_t)(gr + r) * N + gc];
        if (RELU) v = fmaxf(v, 0.f);
        if (VT && gc >= 1024) {
          // V part of QKV: write transposed vt[(b*8+h)][d][s]
          int d = gc - 1024;
          int grr = gr + r;
          int bb2 = grr >> 10, s = grr & 1023;
          vt[(((size_t)(bb2 * 8 + (d >> 6)) * 64 + (d & 63)) << 10) + s] = f2b(v);
        } else if (OUTBF) {
          outb[(size_t)(gr + r) * N + gc] = f2b(v);
        } else {
          outf[(size_t)(gr + r) * N + gc] = v;
        }
      }
    }
  }
}

// ---------------- MFMA flash attention, KVBLK=64, 2 waves/block --------------
// grid (S/32, B*H), 128 threads; wave w owns 16 q-rows q0 = qb*32 + w*16.
// Q,K from qkv (bf16), V from vt [bh][64][1024]. Causal, online softmax.
// plds is per-wave; loop is barrier-free (wave-synchronous LDS use).
__global__ __launch_bounds__(128) void fattn_kernel(
    const ushort* __restrict__ qkv, const ushort* __restrict__ vt,
    ushort* __restrict__ conc) {
  int qb = blockIdx.x;
  int bh = blockIdx.y;
  int b = bh >> 3, h = bh & 7;
  int w = threadIdx.x >> 6, l = threadIdx.x & 63;
  int lane15 = l & 15, lhi = l >> 4;
  int q0 = qb * 32 + w * 16;

  __shared__ __align__(16) ushort plds[2][16][72];

  const ushort* qr = qkv + (size_t)(b * S_ + q0 + lane15) * QKV_N + h * 64;
  short8 qf0 = *(const short8*)(qr + lhi * 8);
  short8 qf1 = *(const short8*)(qr + 32 + lhi * 8);

  f32x4 o[4] = {};
  float m[4], lsum[4];
#pragma unroll
  for (int r = 0; r < 4; r++) { m[r] = -1e30f; lsum[r] = 0.f; }

  const ushort* kbase = qkv + (size_t)b * S_ * QKV_N + 512 + h * 64;
  const ushort* vbase = vt + (size_t)bh * 64 * S_;
  int qtop = q0 + 15;

  for (int kv0 = 0; kv0 <= qtop; kv0 += 64) {
    float sv[4][4];
#pragma unroll
    for (int t = 0; t < 4; t++) {
      if (kv0 + t * 16 <= qtop) {
        const ushort* kr = kbase + (size_t)(kv0 + t * 16 + lane15) * QKV_N;
        short8 kf0 = *(const short8*)(kr + lhi * 8);
        short8 kf1 = *(const short8*)(kr + 32 + lhi * 8);
        f32x4 s = {};
        s = __builtin_amdgcn_mfma_f32_16x16x32_bf16(qf0, kf0, s, 0, 0, 0);
        s = __builtin_amdgcn_mfma_f32_16x16x32_bf16(qf1, kf1, s, 0, 0, 0);
        int kidx = kv0 + t * 16 + lane15;
#pragma unroll
        for (int r = 0; r < 4; r++) {
          float v = s[r] * 0.125f;
          if (kidx > q0 + lhi * 4 + r) v = -1e30f;
          sv[t][r] = v;
        }
      } else {
#pragma unroll
        for (int r = 0; r < 4; r++) sv[t][r] = -1e30f;
      }
    }
    // per-row max over 64 kv cols (4 tiles x 16 lanes in lhi-group)
#pragma unroll
    for (int r = 0; r < 4; r++) {
      float rm = fmaxf(fmaxf(sv[0][r], sv[1][r]), fmaxf(sv[2][r], sv[3][r]));
      rm = fmaxf(rm, __shfl_xor(rm, 1));
      rm = fmaxf(rm, __shfl_xor(rm, 2));
      rm = fmaxf(rm, __shfl_xor(rm, 4));
      rm = fmaxf(rm, __shfl_xor(rm, 8));
      float mn = fmaxf(m[r], rm);
      float sc = __expf(m[r] - mn);
      m[r] = mn;
      float rs = 0.f;
#pragma unroll
      for (int t = 0; t < 4; t++) {
        float p = __expf(sv[t][r] - mn);
        plds[w][lhi * 4 + r][t * 16 + lane15] = f2b(p);
        rs += p;
      }
      rs += __shfl_xor(rs, 1);
      rs += __shfl_xor(rs, 2);
      rs += __shfl_xor(rs, 4);
      rs += __shfl_xor(rs, 8);
      lsum[r] = lsum[r] * sc + rs;
#pragma unroll
      for (int n = 0; n < 4; n++) o[n][r] *= sc;
    }
    // PV: P[16x64] @ V^T tiles
    short8 pa0 = *(const short8*)&plds[w][lane15][lhi * 8];
    short8 pa1 = *(const short8*)&plds[w][lane15][32 + lhi * 8];
#pragma unroll
    for (int n = 0; n < 4; n++) {
      const ushort* vr = vbase + (size_t)(n * 16 + lane15) * S_ + kv0;
      short8 vf0 = *(const short8*)(vr + lhi * 8);
      short8 vf1 = *(const short8*)(vr + 32 + lhi * 8);
      o[n] = __builtin_amdgcn_mfma_f32_16x16x32_bf16(pa0, vf0, o[n], 0, 0, 0);
      o[n] = __builtin_amdgcn_mfma_f32_16x16x32_bf16(pa1, vf1, o[n], 0, 0, 0);
    }
  }
#pragma unroll
  for (int r = 0; r < 4; r++) {
    float inv = 1.f / lsum[r];
    int row = b * S_ + q0 + lhi * 4 + r;
#pragma unroll
    for (int n = 0; n < 4; n++)
      conc[(size_t)row * (H_ * D_) + h * 64 + n * 16 + lane15] = f2b(o[n][r] * inv);
  }
}

// ---------------- layernorm: wave-per-row, one pass (sum + sumsq) ------------
__global__ __launch_bounds__(256) void ln_kernel(
    const float* __restrict__ in, const float* __restrict__ g,
    const float* __restrict__ bsh, float* __restrict__ outf,
    ushort* __restrict__ outb) {
  int w = threadIdx.x >> 6, l = threadIdx.x & 63;
  int row = blockIdx.x * 4 + w;
  const float* r = in + (size_t)row * E_ + l * 8;
  float4 x0 = *(const float4*)r;
  float4 x1 = *(const float4*)(r + 4);
  float s = x0.x + x0.y + x0.z + x0.w + x1.x + x1.y + x1.z + x1.w;
  float q = x0.x * x0.x + x0.y * x0.y + x0.z * x0.z + x0.w * x0.w +
            x1.x * x1.x + x1.y * x1.y + x1.z * x1.z + x1.w * x1.w;
#pragma unroll
  for (int off = 1; off < 64; off <<= 1) {
    s += __shfl_xor(s, off);
    q += __shfl_xor(q, off);
  }
  float mu = s * (1.f / 512.f);
  float var = q * (1.f / 512.f) - mu * mu;
  float rs = rsqrtf(var + 1e-5f);
  float4 g0 = *(const float4*)(g + l * 8);
  float4 g1 = *(const float4*)(g + l * 8 + 4);
  float4 b0 = *(const float4*)(bsh + l * 8);
  float4 b1 = *(const float4*)(bsh + l * 8 + 4);
  float y[8];
  y[0] = (x0.x - mu) * rs * g0.x + b0.x;
  y[1] = (x0.y - mu) * rs * g0.y + b0.y;
  y[2] = (x0.z - mu) * rs * g0.z + b0.z;
  y[3] = (x0.w - mu) * rs * g0.w + b0.w;
  y[4] = (x1.x - mu) * rs * g1.x + b1.x;
  y[5] = (x1.y - mu) * rs * g1.y + b1.y;
  y[6] = (x1.z - mu) * rs * g1.z + b1.z;
  y[7] = (x1.w - mu) * rs * g1.w + b1.w;
  float* of = outf + (size_t)row * E_ + l * 8;
  *(float4*)of = make_float4(y[0], y[1], y[2], y[3]);
  *(float4*)(of + 4) = make_float4(y[4], y[5], y[6], y[7]);
  ushort4 u0 = {f2b(y[0]), f2b(y[1]), f2b(y[2]), f2b(y[3])};
  ushort4 u1 = {f2b(y[4]), f2b(y[5]), f2b(y[6]), f2b(y[7])};
  ushort* ob = outb + (size_t)row * E_ + l * 8;
  *(ushort4*)ob = u0;
  *(ushort4*)(ob + 4) = u1;
}

// ---------------- host ----------------
extern "C" void kernel_launch(void* const* d_in, const int* in_sizes, int n_in,
                              void* d_out, int out_size, void* d_ws, size_t ws_size,
                              hipStream_t stream) {
  const int* x = (const int*)d_in[0];
  const float* tok = (const float*)d_in[1];
  const float* pos = (const float*)d_in[2];
  const float* Wq = (const float*)d_in[3];
  const float* bq = (const float*)d_in[4];
  const float* Wk = (const float*)d_in[5];
  const float* bk = (const float*)d_in[6];
  const float* Wv = (const float*)d_in[7];
  const float* bv = (const float*)d_in[8];
  const float* Wo = (const float*)d_in[9];
  const float* bo = (const float*)d_in[10];
  const float* W1 = (const float*)d_in[11];
  const float* b1 = (const float*)d_in[12];
  const float* W2 = (const float*)d_in[13];
  const float* b2 = (const float*)d_in[14];
  const float* ln1g = (const float*)d_in[15];
  const float* ln1b = (const float*)d_in[16];
  const float* ln2g = (const float*)d_in[17];
  const float* ln2b = (const float*)d_in[18];
  const float* Wout = (const float*)d_in[19];
  const float* bout = (const float*)d_in[20];
  float* out = (float*)d_out;

  char* p = (char*)d_ws;
  auto alloc = [&](size_t bytes) {
    char* r = p;
    p += (bytes + 255) & ~(size_t)255;
    return r;
  };
  float* h_f = (float*)alloc((size_t)M_ * E_ * 4);
  ushort* h_b = (ushort*)alloc((size_t)M_ * E_ * 2);
  ushort* qkv_b = (ushort*)alloc((size_t)M_ * QKV_N * 2);
  ushort* conc_b = (ushort*)alloc((size_t)M_ * E_ * 2);
  float* t_f = (float*)alloc((size_t)M_ * E_ * 4);
  float* ln_f = (float*)alloc((size_t)M_ * E_ * 4);
  ushort* ln_b = (ushort*)alloc((size_t)M_ * E_ * 2);
  ushort* ff_b = (ushort*)alloc((size_t)M_ * FF_ * 2);
  ushort* vt_b = (ushort*)alloc((size_t)B_ * H_ * D_ * S_ * 2);
  ushort* wqkv = (ushort*)alloc((size_t)L_ * QKV_N * E_ * 2);
  float* bqkv = (float*)alloc((size_t)L_ * QKV_N * 4);
  ushort* wo_t = (ushort*)alloc((size_t)L_ * E_ * E_ * 2);
  ushort* w1_t = (ushort*)alloc((size_t)L_ * FF_ * E_ * 2);
  ushort* w2_t = (ushort*)alloc((size_t)L_ * E_ * FF_ * 2);
  ushort* wout_t = (ushort*)alloc((size_t)V_ * E_ * 2);

  // ---- weight conversion ----
  qkvw_kernel<<<dim3(E_ / 32, D_ / 32, 3 * L_ * H_), 256, 0, stream>>>(Wq, Wk, Wv, wqkv);
  transpose_cvt_kernel<<<dim3(16, 16, L_), 256, 0, stream>>>(
      Wo, wo_t, 512, 512, 1, (long long)512 * 512, 0, (long long)512 * 512, 0);
  transpose_cvt_kernel<<<dim3(E_ / 32, FF_ / 32, L_), 256, 0, stream>>>(
      W1, w1_t, E_, FF_, 1, (long long)E_ * FF_, 0, (long long)FF_ * E_, 0);
  transpose_cvt_kernel<<<dim3(FF_ / 32, E_ / 32, L_), 256, 0, stream>>>(
      W2, w2_t, FF_, E_, 1, (long long)FF_ * E_, 0, (long long)E_ * FF_, 0);
  transpose_cvt_kernel<<<dim3(E_ / 32, V_ / 32, 1), 256, 0, stream>>>(
      Wout, wout_t, E_, V_, 1, 0, 0, 0, 0);
  pack_b_kernel<<<(L_ * QKV_N + 255) / 256, 256, 0, stream>>>(bq, bk, bv, bqkv);

  // ---- embedding ----
  embed_kernel<<<(M_ * E_) / 256, 256, 0, stream>>>(x, tok, pos, h_f, h_b);

  for (int l = 0; l < L_; ++l) {
    // QKV: [2048,512] @ [512,1536] -> bf16 (+ fused V transpose into vt_b)
    mfma_gemm_kernel<true, false, true, false><<<(QKV_N / 128) * (M_ / 128), 256, 0, stream>>>(
        h_b, wqkv + (size_t)l * QKV_N * E_, bqkv + l * QKV_N, nullptr,
        qkv_b, vt_b, M_, QKV_N, E_, QKV_N / 128);
    // flash attention
    fattn_kernel<<<dim3(S_ / 32, B_ * H_), 128, 0, stream>>>(qkv_b, vt_b, conc_b);
    // Wo + residual(h_f) -> t_f fp32
    mfma_gemm_kernel<false, false, false, false><<<(E_ / 128) * (M_ / 128), 256, 0, stream>>>(
        conc_b, wo_t + (size_t)l * E_ * E_, bo + l * E_, h_f, t_f, nullptr,
        M_, E_, E_, E_ / 128);
    ln_kernel<<<M_ / 4, 256, 0, stream>>>(t_f, ln1g + l * E_, ln1b + l * E_, ln_f, ln_b);
    // FF1 + ReLU: [2048,512] @ [512,2048] -> bf16
    mfma_gemm_kernel<true, true, false, false><<<(FF_ / 128) * (M_ / 128), 256, 0, stream>>>(
        ln_b, w1_t + (size_t)l * FF_ * E_, b1 + l * FF_, nullptr, ff_b, nullptr,
        M_, FF_, E_, FF_ / 128);
    // FF2 + residual(ln_f): [2048,2048] @ [2048,512] -> t_f fp32
    mfma_gemm_kernel<false, false, false, false><<<(E_ / 128) * (M_ / 128), 256, 0, stream>>>(
        ff_b, w2_t + (size_t)l * E_ * FF_, b2 + l * E_, ln_f, t_f, nullptr,
        M_, E_, FF_, E_ / 128);
    ln_kernel<<<M_ / 4, 256, 0, stream>>>(t_f, ln2g + l * E_, ln2b + l * E_, h_f, h_b);
  }

  // final projection: [2048,512] @ [512,32000] -> fp32 logits (XCD swizzle)
  mfma_gemm_kernel<false, false, false, true><<<(V_ / 128) * (M_ / 128), 256, 0, stream>>>(
      h_b, wout_t, bout, nullptr, out, nullptr, M_, V_, E_, V_ / 128);
}

// Round 5
// 660.241 us; speedup vs baseline: 5.8003x; 1.2896x over previous
//
#include <hip/hip_runtime.h>
#include <hip/hip_bf16.h>

// GPT forward: B=2, S=1024, E=512, H=8, D=64, L=4, FF=2048, V=32000
// Round 5: split-K=4 for Wo/FF2 (64->256 blocks) with reduction fused into LN.
// BK=64 swizzled-LDS MFMA GEMMs, KVBLK=64 flash attention, fused V-transpose.

#define B_ 2
#define S_ 1024
#define E_ 512
#define H_ 8
#define D_ 64
#define L_ 4
#define FF_ 2048
#define V_ 32000
#define M_ (B_ * S_)          // 2048 rows
#define QKV_N (3 * H_ * D_)   // 1536

typedef __attribute__((ext_vector_type(8))) short short8;
typedef __attribute__((ext_vector_type(4))) float f32x4;

__device__ __forceinline__ float b2f(ushort u) {
  union { uint32_t i; float f; } c; c.i = ((uint32_t)u) << 16; return c.f;
}
__device__ __forceinline__ ushort f2b(float f) {
  union { float f; uint32_t i; } c; c.f = f;
  uint32_t u = c.i;
  return (ushort)((u + 0x7FFFu + ((u >> 16) & 1u)) >> 16);
}

__device__ __forceinline__ void gload16(const ushort* g, ushort* l) {
  __builtin_amdgcn_global_load_lds(
      (const __attribute__((address_space(1))) void*)g,
      (__attribute__((address_space(3))) void*)l, 16, 0, 0);
}

// ---------------- embed: h = tok_emb[x] + pos_emb (fp32 + bf16) --------------
__global__ __launch_bounds__(256) void embed_kernel(
    const int* __restrict__ x, const float* __restrict__ tok,
    const float* __restrict__ pos, float* __restrict__ hf,
    ushort* __restrict__ hb) {
  int idx = blockIdx.x * 256 + threadIdx.x;
  int e = idx & (E_ - 1);
  int t = (idx >> 9) & (S_ - 1);
  int b = idx >> 19;
  int tokid = x[b * S_ + t];
  float v = tok[(size_t)tokid * E_ + e] + pos[(size_t)t * E_ + e];
  hf[idx] = v;
  hb[idx] = f2b(v);
}

// ------------- generic tiled transpose+convert fp32 [R][C] -> bf16 [C][R] ----
__global__ __launch_bounds__(256) void transpose_cvt_kernel(
    const float* __restrict__ in, ushort* __restrict__ out, int R, int C,
    int B2, long long inS1, long long inS2, long long outS1, long long outS2) {
  __shared__ float tile[32][33];
  int bz = blockIdx.z;
  int b1 = bz / B2, b2 = bz % B2;
  in += (size_t)b1 * inS1 + (size_t)b2 * inS2;
  out += (size_t)b1 * outS1 + (size_t)b2 * outS2;
  int r0 = blockIdx.x * 32, c0 = blockIdx.y * 32;
  int tx = threadIdx.x & 31, ty = threadIdx.x >> 5;
#pragma unroll
  for (int i = 0; i < 4; i++)
    tile[ty + 8 * i][tx] = in[(size_t)(r0 + ty + 8 * i) * C + c0 + tx];
  __syncthreads();
#pragma unroll
  for (int i = 0; i < 4; i++)
    out[(size_t)(c0 + ty + 8 * i) * R + r0 + tx] = f2b(tile[tx][ty + 8 * i]);
}

// ------------- QKV weights [3][L][H][E][D] -> wqkv [L][t*512+h*64+d][E] ------
__global__ __launch_bounds__(256) void qkvw_kernel(
    const float* __restrict__ Wq, const float* __restrict__ Wk,
    const float* __restrict__ Wv, ushort* __restrict__ wqkv) {
  __shared__ float tile[32][33];
  int bz = blockIdx.z;            // 0..3*L*H-1
  int t = bz / (L_ * H_);
  int rem = bz % (L_ * H_);
  int lyr = rem / H_, h = rem % H_;
  const float* in = ((t == 0) ? Wq : (t == 1) ? Wk : Wv) +
                    ((size_t)lyr * H_ + h) * E_ * D_;
  ushort* out = wqkv + (size_t)lyr * QKV_N * E_ + ((size_t)t * 512 + h * 64) * E_;
  int r0 = blockIdx.x * 32, c0 = blockIdx.y * 32;  // r over E, c over D
  int tx = threadIdx.x & 31, ty = threadIdx.x >> 5;
#pragma unroll
  for (int i = 0; i < 4; i++)
    tile[ty + 8 * i][tx] = in[(size_t)(r0 + ty + 8 * i) * D_ + c0 + tx];
  __syncthreads();
#pragma unroll
  for (int i = 0; i < 4; i++)
    out[(size_t)(c0 + ty + 8 * i) * E_ + r0 + tx] = f2b(tile[tx][ty + 8 * i]);
}

// ---------------- pack QKV biases -> [L][1536] fp32 --------------------------
__global__ __launch_bounds__(256) void pack_b_kernel(
    const float* __restrict__ bq, const float* __restrict__ bk,
    const float* __restrict__ bv, float* __restrict__ bp) {
  int idx = blockIdx.x * 256 + threadIdx.x;
  if (idx >= L_ * QKV_N) return;
  int n = idx % QKV_N;
  int l = idx / QKV_N;
  int t = n / (H_ * D_);
  int hd = n % (H_ * D_);
  const float* src = (t == 0) ? bq : (t == 1) ? bk : bv;
  bp[idx] = src[(size_t)l * H_ * D_ + hd];
}

// ---------------- MFMA GEMM: C[M,N] = A[M,K](bf16) @ Bt[N,K](bf16) -----------
// 128x128 tile, BK=64, 4 waves -> 64x64/wave. XOR-swizzled LDS.
template <bool OUTBF, bool RELU, bool VT, bool SWZ>
__global__ __launch_bounds__(256) void mfma_gemm_kernel(
    const ushort* __restrict__ A, const ushort* __restrict__ Bt,
    const float* __restrict__ bias, const float* __restrict__ resid,
    void* __restrict__ out, ushort* __restrict__ vt,
    int M, int N, int K, int gx) {
  __shared__ __align__(16) ushort As[128 * 64];
  __shared__ __align__(16) ushort Bs[128 * 64];
  int tid = threadIdx.x;
  int w = tid >> 6, l = tid & 63;
  int wr = w >> 1, wc = w & 1;
  int lane15 = l & 15, lhi = l >> 4;

  int bid = blockIdx.x;
  int bx, by;
  if (SWZ) {
    int nwg = gx * (M >> 7);
    int wg = (bid & 7) * (nwg >> 3) + (bid >> 3);
    by = wg & ((M >> 7) - 1);
    bx = wg >> 4;
  } else {
    bx = bid % gx;
    by = bid / gx;
  }
  int row0 = by * 128, col0 = bx * 128;

  int rr8 = l >> 3;
  int ksrc = (((l & 7) ^ rr8) << 3);
  const ushort *gA[2][2], *gB[2][2];
  ushort *lA[2][2], *lB[2][2];
#pragma unroll
  for (int cc = 0; cc < 2; cc++) {
    int c = w + cc * 4;
#pragma unroll
    for (int h = 0; h < 2; h++) {
      int row = c * 16 + h * 8 + rr8;
      gA[cc][h] = A + (size_t)(row0 + row) * K + ksrc;
      gB[cc][h] = Bt + (size_t)(col0 + row) * K + ksrc;
      int ldst = c * 1024 + h * 512 + l * 8;
      lA[cc][h] = &As[ldst];
      lB[cc][h] = &Bs[ldst];
    }
  }

  f32x4 acc[4][4] = {};

  for (int k0 = 0; k0 < K; k0 += 64) {
#pragma unroll
    for (int cc = 0; cc < 2; cc++)
#pragma unroll
      for (int h = 0; h < 2; h++) {
        gload16(gA[cc][h] + k0, lA[cc][h]);
        gload16(gB[cc][h] + k0, lB[cc][h]);
      }
    __syncthreads();
    short8 a[4][2], b[4][2];
    int sa = (lane15 & 7) << 4;
#pragma unroll
    for (int i = 0; i < 4; i++) {
      int ra = (wr * 64 + i * 16 + lane15) * 64;
      int rb = (wc * 64 + i * 16 + lane15) * 64;
#pragma unroll
      for (int kk = 0; kk < 2; kk++) {
        int inner = ((kk * 64 + lhi * 16) ^ sa) >> 1;
        a[i][kk] = *(const short8*)&As[ra + inner];
        b[i][kk] = *(const short8*)&Bs[rb + inner];
      }
    }
#pragma unroll
    for (int i = 0; i < 4; i++)
#pragma unroll
      for (int j = 0; j < 4; j++) {
        acc[i][j] = __builtin_amdgcn_mfma_f32_16x16x32_bf16(a[i][0], b[j][0], acc[i][j], 0, 0, 0);
        acc[i][j] = __builtin_amdgcn_mfma_f32_16x16x32_bf16(a[i][1], b[j][1], acc[i][j], 0, 0, 0);
      }
    __syncthreads();
  }

  float* outf = (float*)out;
  ushort* outb = (ushort*)out;
#pragma unroll
  for (int i = 0; i < 4; i++) {
    int gr = row0 + wr * 64 + i * 16 + lhi * 4;
#pragma unroll
    for (int j = 0; j < 4; j++) {
      int gc = col0 + wc * 64 + j * 16 + lane15;
      float bb = bias[gc];
#pragma unroll
      for (int r = 0; r < 4; r++) {
        float v = acc[i][j][r] + bb;
        if (resid) v += resid[(size_t)(gr + r) * N + gc];
        if (RELU) v = fmaxf(v, 0.f);
        if (VT && gc >= 1024) {
          int d = gc - 1024;
          int grr = gr + r;
          int bb2 = grr >> 10, s = grr & 1023;
          vt[(((size_t)(bb2 * 8 + (d >> 6)) * 64 + (d & 63)) << 10) + s] = f2b(v);
        } else if (OUTBF) {
          outb[(size_t)(gr + r) * N + gc] = f2b(v);
        } else {
          outf[(size_t)(gr + r) * N + gc] = v;
        }
      }
    }
  }
}

// ------------- split-K MFMA GEMM -> fp32 partials [SK][M][N] -----------------
// grid.x = SK * (N/128) * (M/128); no bias/resid (added in ln_red).
template <int SK>
__global__ __launch_bounds__(256) void mfma_gemm_sk_kernel(
    const ushort* __restrict__ A, const ushort* __restrict__ Bt,
    float* __restrict__ part, int M, int N, int K, int gx) {
  __shared__ __align__(16) ushort As[128 * 64];
  __shared__ __align__(16) ushort Bs[128 * 64];
  int tid = threadIdx.x;
  int w = tid >> 6, l = tid & 63;
  int wr = w >> 1, wc = w & 1;
  int lane15 = l & 15, lhi = l >> 4;

  int tiles = gx * (M >> 7);
  int sk = blockIdx.x / tiles;
  int rem = blockIdx.x % tiles;
  int bx = rem % gx, by = rem / gx;
  int row0 = by * 128, col0 = bx * 128;
  int klen = K / SK, kbeg = sk * klen;

  int rr8 = l >> 3;
  int ksrc = (((l & 7) ^ rr8) << 3);
  const ushort *gA[2][2], *gB[2][2];
  ushort *lA[2][2], *lB[2][2];
#pragma unroll
  for (int cc = 0; cc < 2; cc++) {
    int c = w + cc * 4;
#pragma unroll
    for (int h = 0; h < 2; h++) {
      int row = c * 16 + h * 8 + rr8;
      gA[cc][h] = A + (size_t)(row0 + row) * K + ksrc;
      gB[cc][h] = Bt + (size_t)(col0 + row) * K + ksrc;
      int ldst = c * 1024 + h * 512 + l * 8;
      lA[cc][h] = &As[ldst];
      lB[cc][h] = &Bs[ldst];
    }
  }

  f32x4 acc[4][4] = {};

  for (int k0 = kbeg; k0 < kbeg + klen; k0 += 64) {
#pragma unroll
    for (int cc = 0; cc < 2; cc++)
#pragma unroll
      for (int h = 0; h < 2; h++) {
        gload16(gA[cc][h] + k0, lA[cc][h]);
        gload16(gB[cc][h] + k0, lB[cc][h]);
      }
    __syncthreads();
    short8 a[4][2], b[4][2];
    int sa = (lane15 & 7) << 4;
#pragma unroll
    for (int i = 0; i < 4; i++) {
      int ra = (wr * 64 + i * 16 + lane15) * 64;
      int rb = (wc * 64 + i * 16 + lane15) * 64;
#pragma unroll
      for (int kk = 0; kk < 2; kk++) {
        int inner = ((kk * 64 + lhi * 16) ^ sa) >> 1;
        a[i][kk] = *(const short8*)&As[ra + inner];
        b[i][kk] = *(const short8*)&Bs[rb + inner];
      }
    }
#pragma unroll
    for (int i = 0; i < 4; i++)
#pragma unroll
      for (int j = 0; j < 4; j++) {
        acc[i][j] = __builtin_amdgcn_mfma_f32_16x16x32_bf16(a[i][0], b[j][0], acc[i][j], 0, 0, 0);
        acc[i][j] = __builtin_amdgcn_mfma_f32_16x16x32_bf16(a[i][1], b[j][1], acc[i][j], 0, 0, 0);
      }
    __syncthreads();
  }

  float* dst = part + (size_t)sk * M * N;
#pragma unroll
  for (int i = 0; i < 4; i++) {
    int gr = row0 + wr * 64 + i * 16 + lhi * 4;
#pragma unroll
    for (int j = 0; j < 4; j++) {
      int gc = col0 + wc * 64 + j * 16 + lane15;
#pragma unroll
      for (int r = 0; r < 4; r++)
        dst[(size_t)(gr + r) * N + gc] = acc[i][j][r];
    }
  }
}

// ---------------- MFMA flash attention, KVBLK=64, 2 waves/block --------------
__global__ __launch_bounds__(128) void fattn_kernel(
    const ushort* __restrict__ qkv, const ushort* __restrict__ vt,
    ushort* __restrict__ conc) {
  int qb = blockIdx.x;
  int bh = blockIdx.y;
  int b = bh >> 3, h = bh & 7;
  int w = threadIdx.x >> 6, l = threadIdx.x & 63;
  int lane15 = l & 15, lhi = l >> 4;
  int q0 = qb * 32 + w * 16;

  __shared__ __align__(16) ushort plds[2][16][72];

  const ushort* qr = qkv + (size_t)(b * S_ + q0 + lane15) * QKV_N + h * 64;
  short8 qf0 = *(const short8*)(qr + lhi * 8);
  short8 qf1 = *(const short8*)(qr + 32 + lhi * 8);

  f32x4 o[4] = {};
  float m[4], lsum[4];
#pragma unroll
  for (int r = 0; r < 4; r++) { m[r] = -1e30f; lsum[r] = 0.f; }

  const ushort* kbase = qkv + (size_t)b * S_ * QKV_N + 512 + h * 64;
  const ushort* vbase = vt + (size_t)bh * 64 * S_;
  int qtop = q0 + 15;

  for (int kv0 = 0; kv0 <= qtop; kv0 += 64) {
    float sv[4][4];
#pragma unroll
    for (int t = 0; t < 4; t++) {
      if (kv0 + t * 16 <= qtop) {
        const ushort* kr = kbase + (size_t)(kv0 + t * 16 + lane15) * QKV_N;
        short8 kf0 = *(const short8*)(kr + lhi * 8);
        short8 kf1 = *(const short8*)(kr + 32 + lhi * 8);
        f32x4 s = {};
        s = __builtin_amdgcn_mfma_f32_16x16x32_bf16(qf0, kf0, s, 0, 0, 0);
        s = __builtin_amdgcn_mfma_f32_16x16x32_bf16(qf1, kf1, s, 0, 0, 0);
        int kidx = kv0 + t * 16 + lane15;
#pragma unroll
        for (int r = 0; r < 4; r++) {
          float v = s[r] * 0.125f;
          if (kidx > q0 + lhi * 4 + r) v = -1e30f;
          sv[t][r] = v;
        }
      } else {
#pragma unroll
        for (int r = 0; r < 4; r++) sv[t][r] = -1e30f;
      }
    }
#pragma unroll
    for (int r = 0; r < 4; r++) {
      float rm = fmaxf(fmaxf(sv[0][r], sv[1][r]), fmaxf(sv[2][r], sv[3][r]));
      rm = fmaxf(rm, __shfl_xor(rm, 1));
      rm = fmaxf(rm, __shfl_xor(rm, 2));
      rm = fmaxf(rm, __shfl_xor(rm, 4));
      rm = fmaxf(rm, __shfl_xor(rm, 8));
      float mn = fmaxf(m[r], rm);
      float sc = __expf(m[r] - mn);
      m[r] = mn;
      float rs = 0.f;
#pragma unroll
      for (int t = 0; t < 4; t++) {
        float p = __expf(sv[t][r] - mn);
        plds[w][lhi * 4 + r][t * 16 + lane15] = f2b(p);
        rs += p;
      }
      rs += __shfl_xor(rs, 1);
      rs += __shfl_xor(rs, 2);
      rs += __shfl_xor(rs, 4);
      rs += __shfl_xor(rs, 8);
      lsum[r] = lsum[r] * sc + rs;
#pragma unroll
      for (int n = 0; n < 4; n++) o[n][r] *= sc;
    }
    short8 pa0 = *(const short8*)&plds[w][lane15][lhi * 8];
    short8 pa1 = *(const short8*)&plds[w][lane15][32 + lhi * 8];
#pragma unroll
    for (int n = 0; n < 4; n++) {
      const ushort* vr = vbase + (size_t)(n * 16 + lane15) * S_ + kv0;
      short8 vf0 = *(const short8*)(vr + lhi * 8);
      short8 vf1 = *(const short8*)(vr + 32 + lhi * 8);
      o[n] = __builtin_amdgcn_mfma_f32_16x16x32_bf16(pa0, vf0, o[n], 0, 0, 0);
      o[n] = __builtin_amdgcn_mfma_f32_16x16x32_bf16(pa1, vf1, o[n], 0, 0, 0);
    }
  }
#pragma unroll
  for (int r = 0; r < 4; r++) {
    float inv = 1.f / lsum[r];
    int row = b * S_ + q0 + lhi * 4 + r;
#pragma unroll
    for (int n = 0; n < 4; n++)
      conc[(size_t)row * (H_ * D_) + h * 64 + n * 16 + lane15] = f2b(o[n][r] * inv);
  }
}

// ------- layernorm over split-K partials: y = LN(Σ part + bias + resid) ------
// wave-per-row; also the only consumer of the partials (fused reduction).
template <int SK>
__global__ __launch_bounds__(256) void ln_red_kernel(
    const float* __restrict__ part, const float* __restrict__ bias,
    const float* __restrict__ resid, const float* __restrict__ g,
    const float* __restrict__ bsh, float* __restrict__ outf,
    ushort* __restrict__ outb) {
  int w = threadIdx.x >> 6, l = threadIdx.x & 63;
  int row = blockIdx.x * 4 + w;
  size_t off = (size_t)row * E_ + l * 8;
  float4 r0 = *(const float4*)(resid + off);
  float4 r1 = *(const float4*)(resid + off + 4);
  float4 bb0 = *(const float4*)(bias + l * 8);
  float4 bb1 = *(const float4*)(bias + l * 8 + 4);
  float x[8] = {r0.x + bb0.x, r0.y + bb0.y, r0.z + bb0.z, r0.w + bb0.w,
                r1.x + bb1.x, r1.y + bb1.y, r1.z + bb1.z, r1.w + bb1.w};
#pragma unroll
  for (int s = 0; s < SK; s++) {
    const float* ps = part + (size_t)s * M_ * E_ + off;
    float4 p0 = *(const float4*)ps;
    float4 p1 = *(const float4*)(ps + 4);
    x[0] += p0.x; x[1] += p0.y; x[2] += p0.z; x[3] += p0.w;
    x[4] += p1.x; x[5] += p1.y; x[6] += p1.z; x[7] += p1.w;
  }
  float s = 0.f, q = 0.f;
#pragma unroll
  for (int i = 0; i < 8; i++) { s += x[i]; q += x[i] * x[i]; }
#pragma unroll
  for (int off2 = 1; off2 < 64; off2 <<= 1) {
    s += __shfl_xor(s, off2);
    q += __shfl_xor(q, off2);
  }
  float mu = s * (1.f / 512.f);
  float var = q * (1.f / 512.f) - mu * mu;
  float rs = rsqrtf(var + 1e-5f);
  float4 g0 = *(const float4*)(g + l * 8);
  float4 g1 = *(const float4*)(g + l * 8 + 4);
  float4 b0 = *(const float4*)(bsh + l * 8);
  float4 b1 = *(const float4*)(bsh + l * 8 + 4);
  float gg[8] = {g0.x, g0.y, g0.z, g0.w, g1.x, g1.y, g1.z, g1.w};
  float bbv[8] = {b0.x, b0.y, b0.z, b0.w, b1.x, b1.y, b1.z, b1.w};
  float y[8];
#pragma unroll
  for (int i = 0; i < 8; i++) y[i] = (x[i] - mu) * rs * gg[i] + bbv[i];
  float* of = outf + off;
  *(float4*)of = make_float4(y[0], y[1], y[2], y[3]);
  *(float4*)(of + 4) = make_float4(y[4], y[5], y[6], y[7]);
  ushort4 u0 = {f2b(y[0]), f2b(y[1]), f2b(y[2]), f2b(y[3])};
  ushort4 u1 = {f2b(y[4]), f2b(y[5]), f2b(y[6]), f2b(y[7])};
  ushort* ob = outb + off;
  *(ushort4*)ob = u0;
  *(ushort4*)(ob + 4) = u1;
}

// ---------------- host ----------------
extern "C" void kernel_launch(void* const* d_in, const int* in_sizes, int n_in,
                              void* d_out, int out_size, void* d_ws, size_t ws_size,
                              hipStream_t stream) {
  const int* x = (const int*)d_in[0];
  const float* tok = (const float*)d_in[1];
  const float* pos = (const float*)d_in[2];
  const float* Wq = (const float*)d_in[3];
  const float* bq = (const float*)d_in[4];
  const float* Wk = (const float*)d_in[5];
  const float* bk = (const float*)d_in[6];
  const float* Wv = (const float*)d_in[7];
  const float* bv = (const float*)d_in[8];
  const float* Wo = (const float*)d_in[9];
  const float* bo = (const float*)d_in[10];
  const float* W1 = (const float*)d_in[11];
  const float* b1 = (const float*)d_in[12];
  const float* W2 = (const float*)d_in[13];
  const float* b2 = (const float*)d_in[14];
  const float* ln1g = (const float*)d_in[15];
  const float* ln1b = (const float*)d_in[16];
  const float* ln2g = (const float*)d_in[17];
  const float* ln2b = (const float*)d_in[18];
  const float* Wout = (const float*)d_in[19];
  const float* bout = (const float*)d_in[20];
  float* out = (float*)d_out;

  char* p = (char*)d_ws;
  auto alloc = [&](size_t bytes) {
    char* r = p;
    p += (bytes + 255) & ~(size_t)255;
    return r;
  };
  float* h_f = (float*)alloc((size_t)M_ * E_ * 4);
  ushort* h_b = (ushort*)alloc((size_t)M_ * E_ * 2);
  ushort* qkv_b = (ushort*)alloc((size_t)M_ * QKV_N * 2);
  ushort* conc_b = (ushort*)alloc((size_t)M_ * E_ * 2);
  float* part = (float*)alloc((size_t)4 * M_ * E_ * 4);   // split-K partials
  float* ln_f = (float*)alloc((size_t)M_ * E_ * 4);
  ushort* ln_b = (ushort*)alloc((size_t)M_ * E_ * 2);
  ushort* ff_b = (ushort*)alloc((size_t)M_ * FF_ * 2);
  ushort* vt_b = (ushort*)alloc((size_t)B_ * H_ * D_ * S_ * 2);
  ushort* wqkv = (ushort*)alloc((size_t)L_ * QKV_N * E_ * 2);
  float* bqkv = (float*)alloc((size_t)L_ * QKV_N * 4);
  ushort* wo_t = (ushort*)alloc((size_t)L_ * E_ * E_ * 2);
  ushort* w1_t = (ushort*)alloc((size_t)L_ * FF_ * E_ * 2);
  ushort* w2_t = (ushort*)alloc((size_t)L_ * E_ * FF_ * 2);
  ushort* wout_t = (ushort*)alloc((size_t)V_ * E_ * 2);

  // ---- weight conversion ----
  qkvw_kernel<<<dim3(E_ / 32, D_ / 32, 3 * L_ * H_), 256, 0, stream>>>(Wq, Wk, Wv, wqkv);
  transpose_cvt_kernel<<<dim3(16, 16, L_), 256, 0, stream>>>(
      Wo, wo_t, 512, 512, 1, (long long)512 * 512, 0, (long long)512 * 512, 0);
  transpose_cvt_kernel<<<dim3(E_ / 32, FF_ / 32, L_), 256, 0, stream>>>(
      W1, w1_t, E_, FF_, 1, (long long)E_ * FF_, 0, (long long)FF_ * E_, 0);
  transpose_cvt_kernel<<<dim3(FF_ / 32, E_ / 32, L_), 256, 0, stream>>>(
      W2, w2_t, FF_, E_, 1, (long long)FF_ * E_, 0, (long long)E_ * FF_, 0);
  transpose_cvt_kernel<<<dim3(E_ / 32, V_ / 32, 1), 256, 0, stream>>>(
      Wout, wout_t, E_, V_, 1, 0, 0, 0, 0);
  pack_b_kernel<<<(L_ * QKV_N + 255) / 256, 256, 0, stream>>>(bq, bk, bv, bqkv);

  // ---- embedding ----
  embed_kernel<<<(M_ * E_) / 256, 256, 0, stream>>>(x, tok, pos, h_f, h_b);

  for (int l = 0; l < L_; ++l) {
    // QKV: [2048,512] @ [512,1536] -> bf16 (+ fused V transpose into vt_b)
    mfma_gemm_kernel<true, false, true, false><<<(QKV_N / 128) * (M_ / 128), 256, 0, stream>>>(
        h_b, wqkv + (size_t)l * QKV_N * E_, bqkv + l * QKV_N, nullptr,
        qkv_b, vt_b, M_, QKV_N, E_, QKV_N / 128);
    // flash attention
    fattn_kernel<<<dim3(S_ / 32, B_ * H_), 128, 0, stream>>>(qkv_b, vt_b, conc_b);
    // Wo split-K=4 -> partials; LN1 fuses reduction + bias + residual(h_f)
    mfma_gemm_sk_kernel<4><<<4 * (E_ / 128) * (M_ / 128), 256, 0, stream>>>(
        conc_b, wo_t + (size_t)l * E_ * E_, part, M_, E_, E_, E_ / 128);
    ln_red_kernel<4><<<M_ / 4, 256, 0, stream>>>(
        part, bo + l * E_, h_f, ln1g + l * E_, ln1b + l * E_, ln_f, ln_b);
    // FF1 + ReLU: [2048,512] @ [512,2048] -> bf16
    mfma_gemm_kernel<true, true, false, false><<<(FF_ / 128) * (M_ / 128), 256, 0, stream>>>(
        ln_b, w1_t + (size_t)l * FF_ * E_, b1 + l * FF_, nullptr, ff_b, nullptr,
        M_, FF_, E_, FF_ / 128);
    // FF2 split-K=4 -> partials; LN2 fuses reduction + bias + residual(ln_f)
    mfma_gemm_sk_kernel<4><<<4 * (E_ / 128) * (M_ / 128), 256, 0, stream>>>(
        ff_b, w2_t + (size_t)l * E_ * FF_, part, M_, E_, FF_, E_ / 128);
    ln_red_kernel<4><<<M_ / 4, 256, 0, stream>>>(
        part, b2 + l * E_, ln_f, ln2g + l * E_, ln2b + l * E_, h_f, h_b);
  }

  // final projection: [2048,512] @ [512,32000] -> fp32 logits (XCD swizzle)
  mfma_gemm_kernel<false, false, false, true><<<(V_ / 128) * (M_ / 128), 256, 0, stream>>>(
      h_b, wout_t, bout, nullptr, out, nullptr, M_, V_, E_, V_ / 128);
}

// Round 6
// 651.918 us; speedup vs baseline: 5.8744x; 1.0128x over previous
//
#include <hip/hip_runtime.h>
#include <hip/hip_bf16.h>

// GPT forward: B=2, S=1024, E=512, H=8, D=64, L=4, FF=2048, V=32000
// Round 6: final GEMM -> 256^2 tile, 8 waves, double-buffered 2-phase
// (stage t+1 before compute t), XCD-chunked; rest unchanged from round 5.

#define B_ 2
#define S_ 1024
#define E_ 512
#define H_ 8
#define D_ 64
#define L_ 4
#define FF_ 2048
#define V_ 32000
#define M_ (B_ * S_)          // 2048 rows
#define QKV_N (3 * H_ * D_)   // 1536

typedef __attribute__((ext_vector_type(8))) short short8;
typedef __attribute__((ext_vector_type(4))) float f32x4;

__device__ __forceinline__ float b2f(ushort u) {
  union { uint32_t i; float f; } c; c.i = ((uint32_t)u) << 16; return c.f;
}
__device__ __forceinline__ ushort f2b(float f) {
  union { float f; uint32_t i; } c; c.f = f;
  uint32_t u = c.i;
  return (ushort)((u + 0x7FFFu + ((u >> 16) & 1u)) >> 16);
}

__device__ __forceinline__ void gload16(const ushort* g, ushort* l) {
  __builtin_amdgcn_global_load_lds(
      (const __attribute__((address_space(1))) void*)g,
      (__attribute__((address_space(3))) void*)l, 16, 0, 0);
}

// ---------------- embed: h = tok_emb[x] + pos_emb (fp32 + bf16) --------------
__global__ __launch_bounds__(256) void embed_kernel(
    const int* __restrict__ x, const float* __restrict__ tok,
    const float* __restrict__ pos, float* __restrict__ hf,
    ushort* __restrict__ hb) {
  int idx = blockIdx.x * 256 + threadIdx.x;
  int e = idx & (E_ - 1);
  int t = (idx >> 9) & (S_ - 1);
  int b = idx >> 19;
  int tokid = x[b * S_ + t];
  float v = tok[(size_t)tokid * E_ + e] + pos[(size_t)t * E_ + e];
  hf[idx] = v;
  hb[idx] = f2b(v);
}

// ------------- generic tiled transpose+convert fp32 [R][C] -> bf16 [C][R] ----
__global__ __launch_bounds__(256) void transpose_cvt_kernel(
    const float* __restrict__ in, ushort* __restrict__ out, int R, int C,
    int B2, long long inS1, long long inS2, long long outS1, long long outS2) {
  __shared__ float tile[32][33];
  int bz = blockIdx.z;
  int b1 = bz / B2, b2 = bz % B2;
  in += (size_t)b1 * inS1 + (size_t)b2 * inS2;
  out += (size_t)b1 * outS1 + (size_t)b2 * outS2;
  int r0 = blockIdx.x * 32, c0 = blockIdx.y * 32;
  int tx = threadIdx.x & 31, ty = threadIdx.x >> 5;
#pragma unroll
  for (int i = 0; i < 4; i++)
    tile[ty + 8 * i][tx] = in[(size_t)(r0 + ty + 8 * i) * C + c0 + tx];
  __syncthreads();
#pragma unroll
  for (int i = 0; i < 4; i++)
    out[(size_t)(c0 + ty + 8 * i) * R + r0 + tx] = f2b(tile[tx][ty + 8 * i]);
}

// ------------- QKV weights [3][L][H][E][D] -> wqkv [L][t*512+h*64+d][E] ------
__global__ __launch_bounds__(256) void qkvw_kernel(
    const float* __restrict__ Wq, const float* __restrict__ Wk,
    const float* __restrict__ Wv, ushort* __restrict__ wqkv) {
  __shared__ float tile[32][33];
  int bz = blockIdx.z;            // 0..3*L*H-1
  int t = bz / (L_ * H_);
  int rem = bz % (L_ * H_);
  int lyr = rem / H_, h = rem % H_;
  const float* in = ((t == 0) ? Wq : (t == 1) ? Wk : Wv) +
                    ((size_t)lyr * H_ + h) * E_ * D_;
  ushort* out = wqkv + (size_t)lyr * QKV_N * E_ + ((size_t)t * 512 + h * 64) * E_;
  int r0 = blockIdx.x * 32, c0 = blockIdx.y * 32;  // r over E, c over D
  int tx = threadIdx.x & 31, ty = threadIdx.x >> 5;
#pragma unroll
  for (int i = 0; i < 4; i++)
    tile[ty + 8 * i][tx] = in[(size_t)(r0 + ty + 8 * i) * D_ + c0 + tx];
  __syncthreads();
#pragma unroll
  for (int i = 0; i < 4; i++)
    out[(size_t)(c0 + ty + 8 * i) * E_ + r0 + tx] = f2b(tile[tx][ty + 8 * i]);
}

// ---------------- pack QKV biases -> [L][1536] fp32 --------------------------
__global__ __launch_bounds__(256) void pack_b_kernel(
    const float* __restrict__ bq, const float* __restrict__ bk,
    const float* __restrict__ bv, float* __restrict__ bp) {
  int idx = blockIdx.x * 256 + threadIdx.x;
  if (idx >= L_ * QKV_N) return;
  int n = idx % QKV_N;
  int l = idx / QKV_N;
  int t = n / (H_ * D_);
  int hd = n % (H_ * D_);
  const float* src = (t == 0) ? bq : (t == 1) ? bk : bv;
  bp[idx] = src[(size_t)l * H_ * D_ + hd];
}

// ---------------- MFMA GEMM: C[M,N] = A[M,K](bf16) @ Bt[N,K](bf16) -----------
// 128x128 tile, BK=64, 4 waves -> 64x64/wave. XOR-swizzled LDS.
template <bool OUTBF, bool RELU, bool VT>
__global__ __launch_bounds__(256) void mfma_gemm_kernel(
    const ushort* __restrict__ A, const ushort* __restrict__ Bt,
    const float* __restrict__ bias, const float* __restrict__ resid,
    void* __restrict__ out, ushort* __restrict__ vt,
    int M, int N, int K, int gx) {
  __shared__ __align__(16) ushort As[128 * 64];
  __shared__ __align__(16) ushort Bs[128 * 64];
  int tid = threadIdx.x;
  int w = tid >> 6, l = tid & 63;
  int wr = w >> 1, wc = w & 1;
  int lane15 = l & 15, lhi = l >> 4;

  int bid = blockIdx.x;
  int bx = bid % gx, by = bid / gx;
  int row0 = by * 128, col0 = bx * 128;

  int rr8 = l >> 3;
  int ksrc = (((l & 7) ^ rr8) << 3);
  const ushort *gA[2][2], *gB[2][2];
  ushort *lA[2][2], *lB[2][2];
#pragma unroll
  for (int cc = 0; cc < 2; cc++) {
    int c = w + cc * 4;
#pragma unroll
    for (int h = 0; h < 2; h++) {
      int row = c * 16 + h * 8 + rr8;
      gA[cc][h] = A + (size_t)(row0 + row) * K + ksrc;
      gB[cc][h] = Bt + (size_t)(col0 + row) * K + ksrc;
      int ldst = c * 1024 + h * 512 + l * 8;
      lA[cc][h] = &As[ldst];
      lB[cc][h] = &Bs[ldst];
    }
  }

  f32x4 acc[4][4] = {};

  for (int k0 = 0; k0 < K; k0 += 64) {
#pragma unroll
    for (int cc = 0; cc < 2; cc++)
#pragma unroll
      for (int h = 0; h < 2; h++) {
        gload16(gA[cc][h] + k0, lA[cc][h]);
        gload16(gB[cc][h] + k0, lB[cc][h]);
      }
    __syncthreads();
    short8 a[4][2], b[4][2];
    int sa = (lane15 & 7) << 4;
#pragma unroll
    for (int i = 0; i < 4; i++) {
      int ra = (wr * 64 + i * 16 + lane15) * 64;
      int rb = (wc * 64 + i * 16 + lane15) * 64;
#pragma unroll
      for (int kk = 0; kk < 2; kk++) {
        int inner = ((kk * 64 + lhi * 16) ^ sa) >> 1;
        a[i][kk] = *(const short8*)&As[ra + inner];
        b[i][kk] = *(const short8*)&Bs[rb + inner];
      }
    }
#pragma unroll
    for (int i = 0; i < 4; i++)
#pragma unroll
      for (int j = 0; j < 4; j++) {
        acc[i][j] = __builtin_amdgcn_mfma_f32_16x16x32_bf16(a[i][0], b[j][0], acc[i][j], 0, 0, 0);
        acc[i][j] = __builtin_amdgcn_mfma_f32_16x16x32_bf16(a[i][1], b[j][1], acc[i][j], 0, 0, 0);
      }
    __syncthreads();
  }

  float* outf = (float*)out;
  ushort* outb = (ushort*)out;
#pragma unroll
  for (int i = 0; i < 4; i++) {
    int gr = row0 + wr * 64 + i * 16 + lhi * 4;
#pragma unroll
    for (int j = 0; j < 4; j++) {
      int gc = col0 + wc * 64 + j * 16 + lane15;
      float bb = bias[gc];
#pragma unroll
      for (int r = 0; r < 4; r++) {
        float v = acc[i][j][r] + bb;
        if (resid) v += resid[(size_t)(gr + r) * N + gc];
        if (RELU) v = fmaxf(v, 0.f);
        if (VT && gc >= 1024) {
          int d = gc - 1024;
          int grr = gr + r;
          int bb2 = grr >> 10, s = grr & 1023;
          vt[(((size_t)(bb2 * 8 + (d >> 6)) * 64 + (d & 63)) << 10) + s] = f2b(v);
        } else if (OUTBF) {
          outb[(size_t)(gr + r) * N + gc] = f2b(v);
        } else {
          outf[(size_t)(gr + r) * N + gc] = v;
        }
      }
    }
  }
}

// ------------- split-K MFMA GEMM -> fp32 partials [SK][M][N] -----------------
template <int SK>
__global__ __launch_bounds__(256) void mfma_gemm_sk_kernel(
    const ushort* __restrict__ A, const ushort* __restrict__ Bt,
    float* __restrict__ part, int M, int N, int K, int gx) {
  __shared__ __align__(16) ushort As[128 * 64];
  __shared__ __align__(16) ushort Bs[128 * 64];
  int tid = threadIdx.x;
  int w = tid >> 6, l = tid & 63;
  int wr = w >> 1, wc = w & 1;
  int lane15 = l & 15, lhi = l >> 4;

  int tiles = gx * (M >> 7);
  int sk = blockIdx.x / tiles;
  int rem = blockIdx.x % tiles;
  int bx = rem % gx, by = rem / gx;
  int row0 = by * 128, col0 = bx * 128;
  int klen = K / SK, kbeg = sk * klen;

  int rr8 = l >> 3;
  int ksrc = (((l & 7) ^ rr8) << 3);
  const ushort *gA[2][2], *gB[2][2];
  ushort *lA[2][2], *lB[2][2];
#pragma unroll
  for (int cc = 0; cc < 2; cc++) {
    int c = w + cc * 4;
#pragma unroll
    for (int h = 0; h < 2; h++) {
      int row = c * 16 + h * 8 + rr8;
      gA[cc][h] = A + (size_t)(row0 + row) * K + ksrc;
      gB[cc][h] = Bt + (size_t)(col0 + row) * K + ksrc;
      int ldst = c * 1024 + h * 512 + l * 8;
      lA[cc][h] = &As[ldst];
      lB[cc][h] = &Bs[ldst];
    }
  }

  f32x4 acc[4][4] = {};

  for (int k0 = kbeg; k0 < kbeg + klen; k0 += 64) {
#pragma unroll
    for (int cc = 0; cc < 2; cc++)
#pragma unroll
      for (int h = 0; h < 2; h++) {
        gload16(gA[cc][h] + k0, lA[cc][h]);
        gload16(gB[cc][h] + k0, lB[cc][h]);
      }
    __syncthreads();
    short8 a[4][2], b[4][2];
    int sa = (lane15 & 7) << 4;
#pragma unroll
    for (int i = 0; i < 4; i++) {
      int ra = (wr * 64 + i * 16 + lane15) * 64;
      int rb = (wc * 64 + i * 16 + lane15) * 64;
#pragma unroll
      for (int kk = 0; kk < 2; kk++) {
        int inner = ((kk * 64 + lhi * 16) ^ sa) >> 1;
        a[i][kk] = *(const short8*)&As[ra + inner];
        b[i][kk] = *(const short8*)&Bs[rb + inner];
      }
    }
#pragma unroll
    for (int i = 0; i < 4; i++)
#pragma unroll
      for (int j = 0; j < 4; j++) {
        acc[i][j] = __builtin_amdgcn_mfma_f32_16x16x32_bf16(a[i][0], b[j][0], acc[i][j], 0, 0, 0);
        acc[i][j] = __builtin_amdgcn_mfma_f32_16x16x32_bf16(a[i][1], b[j][1], acc[i][j], 0, 0, 0);
      }
    __syncthreads();
  }

  float* dst = part + (size_t)sk * M * N;
#pragma unroll
  for (int i = 0; i < 4; i++) {
    int gr = row0 + wr * 64 + i * 16 + lhi * 4;
#pragma unroll
    for (int j = 0; j < 4; j++) {
      int gc = col0 + wc * 64 + j * 16 + lane15;
#pragma unroll
      for (int r = 0; r < 4; r++)
        dst[(size_t)(gr + r) * N + gc] = acc[i][j][r];
    }
  }
}

// -------- final GEMM: 256x256 tile, 8 waves, 2-phase double-buffered ---------
// C[M,N] = A[M,K] @ Bt[N,K] + bias, fp32 out. Grid = (M/256)*(N/256) = 1000.
// Stage(t+1) issued BEFORE compute(t); __syncthreads drains vmcnt at barrier.
__global__ __launch_bounds__(512) void mfma_gemm256_kernel(
    const ushort* __restrict__ A, const ushort* __restrict__ Bt,
    const float* __restrict__ bias, float* __restrict__ out,
    int M, int N, int K) {
  __shared__ __align__(16) ushort As[2][256 * 64];   // 64 KB
  __shared__ __align__(16) ushort Bs[2][256 * 64];   // 64 KB
  int tid = threadIdx.x;
  int w = tid >> 6, l = tid & 63;
  int wr = w >> 2, wc = w & 3;              // 2 x 4 wave grid -> 128x64 each
  int lane15 = l & 15, lhi = l >> 4;

  // XCD chunking: 1000 blocks = 8 chunks x 125; by-major inside a chunk so
  // the 8 row-blocks sharing one 256KB B-panel run on one XCD's L2.
  int bid = blockIdx.x;
  int wg = (bid & 7) * 125 + (bid >> 3);
  int by = wg & 7, bx = wg >> 3;
  int row0 = by * 256, col0 = bx * 256;

  // staging: 4 passes x 512 threads x 16B per matrix per K-step (BK=64)
  const ushort* ga[4];
  const ushort* gb[4];
  int lofs[4];
#pragma unroll
  for (int p2 = 0; p2 < 4; p2++) {
    int i = p2 * 512 + tid;
    int row = i >> 3, kg = i & 7;
    int ksrc = ((kg ^ (row & 7)) << 3);     // pre-swizzled global k-group
    ga[p2] = A + (size_t)(row0 + row) * K + ksrc;
    gb[p2] = Bt + (size_t)(col0 + row) * K + ksrc;
    lofs[p2] = i * 8;                       // linear LDS dest (ushort idx)
  }

  f32x4 acc[8][4] = {};

  auto stage = [&](int buf, int k0) {
    ushort* bA = &As[buf][0];
    ushort* bB = &Bs[buf][0];
#pragma unroll
    for (int p2 = 0; p2 < 4; p2++) {
      gload16(ga[p2] + k0, bA + lofs[p2]);
      gload16(gb[p2] + k0, bB + lofs[p2]);
    }
  };
  auto compute = [&](int buf) {
    const ushort* bA = &As[buf][0];
    const ushort* bB = &Bs[buf][0];
    int sa = (lane15 & 7) << 4;
#pragma unroll
    for (int kk = 0; kk < 2; kk++) {
      int inner = ((kk * 64 + lhi * 16) ^ sa) >> 1;
      short8 a[8], b[4];
#pragma unroll
      for (int i = 0; i < 8; i++)
        a[i] = *(const short8*)&bA[(wr * 128 + i * 16 + lane15) * 64 + inner];
#pragma unroll
      for (int j = 0; j < 4; j++)
        b[j] = *(const short8*)&bB[(wc * 64 + j * 16 + lane15) * 64 + inner];
#pragma unroll
      for (int i = 0; i < 8; i++)
#pragma unroll
        for (int j = 0; j < 4; j++)
          acc[i][j] = __builtin_amdgcn_mfma_f32_16x16x32_bf16(a[i], b[j], acc[i][j], 0, 0, 0);
    }
  };

  stage(0, 0);
  __syncthreads();
  int cur = 0;
  int nt = K >> 6;
  for (int t = 0; t < nt - 1; t++) {
    stage(cur ^ 1, (t + 1) << 6);   // issue next-tile loads first
    compute(cur);                   // ds_read + MFMA on current tile
    __syncthreads();                // drains vmcnt+lgkmcnt, flips buffer
    cur ^= 1;
  }
  compute(cur);

#pragma unroll
  for (int i = 0; i < 8; i++) {
    int gr = row0 + wr * 128 + i * 16 + lhi * 4;
#pragma unroll
    for (int j = 0; j < 4; j++) {
      int gc = col0 + wc * 64 + j * 16 + lane15;
      float bb = bias[gc];
#pragma unroll
      for (int r = 0; r < 4; r++)
        out[(size_t)(gr + r) * N + gc] = acc[i][j][r] + bb;
    }
  }
}

// ---------------- MFMA flash attention, KVBLK=64, 2 waves/block --------------
__global__ __launch_bounds__(128) void fattn_kernel(
    const ushort* __restrict__ qkv, const ushort* __restrict__ vt,
    ushort* __restrict__ conc) {
  int qb = blockIdx.x;
  int bh = blockIdx.y;
  int b = bh >> 3, h = bh & 7;
  int w = threadIdx.x >> 6, l = threadIdx.x & 63;
  int lane15 = l & 15, lhi = l >> 4;
  int q0 = qb * 32 + w * 16;

  __shared__ __align__(16) ushort plds[2][16][72];

  const ushort* qr = qkv + (size_t)(b * S_ + q0 + lane15) * QKV_N + h * 64;
  short8 qf0 = *(const short8*)(qr + lhi * 8);
  short8 qf1 = *(const short8*)(qr + 32 + lhi * 8);

  f32x4 o[4] = {};
  float m[4], lsum[4];
#pragma unroll
  for (int r = 0; r < 4; r++) { m[r] = -1e30f; lsum[r] = 0.f; }

  const ushort* kbase = qkv + (size_t)b * S_ * QKV_N + 512 + h * 64;
  const ushort* vbase = vt + (size_t)bh * 64 * S_;
  int qtop = q0 + 15;

  for (int kv0 = 0; kv0 <= qtop; kv0 += 64) {
    float sv[4][4];
#pragma unroll
    for (int t = 0; t < 4; t++) {
      if (kv0 + t * 16 <= qtop) {
        const ushort* kr = kbase + (size_t)(kv0 + t * 16 + lane15) * QKV_N;
        short8 kf0 = *(const short8*)(kr + lhi * 8);
        short8 kf1 = *(const short8*)(kr + 32 + lhi * 8);
        f32x4 s = {};
        s = __builtin_amdgcn_mfma_f32_16x16x32_bf16(qf0, kf0, s, 0, 0, 0);
        s = __builtin_amdgcn_mfma_f32_16x16x32_bf16(qf1, kf1, s, 0, 0, 0);
        int kidx = kv0 + t * 16 + lane15;
#pragma unroll
        for (int r = 0; r < 4; r++) {
          float v = s[r] * 0.125f;
          if (kidx > q0 + lhi * 4 + r) v = -1e30f;
          sv[t][r] = v;
        }
      } else {
#pragma unroll
        for (int r = 0; r < 4; r++) sv[t][r] = -1e30f;
      }
    }
#pragma unroll
    for (int r = 0; r < 4; r++) {
      float rm = fmaxf(fmaxf(sv[0][r], sv[1][r]), fmaxf(sv[2][r], sv[3][r]));
      rm = fmaxf(rm, __shfl_xor(rm, 1));
      rm = fmaxf(rm, __shfl_xor(rm, 2));
      rm = fmaxf(rm, __shfl_xor(rm, 4));
      rm = fmaxf(rm, __shfl_xor(rm, 8));
      float mn = fmaxf(m[r], rm);
      float sc = __expf(m[r] - mn);
      m[r] = mn;
      float rs = 0.f;
#pragma unroll
      for (int t = 0; t < 4; t++) {
        float p = __expf(sv[t][r] - mn);
        plds[w][lhi * 4 + r][t * 16 + lane15] = f2b(p);
        rs += p;
      }
      rs += __shfl_xor(rs, 1);
      rs += __shfl_xor(rs, 2);
      rs += __shfl_xor(rs, 4);
      rs += __shfl_xor(rs, 8);
      lsum[r] = lsum[r] * sc + rs;
#pragma unroll
      for (int n = 0; n < 4; n++) o[n][r] *= sc;
    }
    short8 pa0 = *(const short8*)&plds[w][lane15][lhi * 8];
    short8 pa1 = *(const short8*)&plds[w][lane15][32 + lhi * 8];
#pragma unroll
    for (int n = 0; n < 4; n++) {
      const ushort* vr = vbase + (size_t)(n * 16 + lane15) * S_ + kv0;
      short8 vf0 = *(const short8*)(vr + lhi * 8);
      short8 vf1 = *(const short8*)(vr + 32 + lhi * 8);
      o[n] = __builtin_amdgcn_mfma_f32_16x16x32_bf16(pa0, vf0, o[n], 0, 0, 0);
      o[n] = __builtin_amdgcn_mfma_f32_16x16x32_bf16(pa1, vf1, o[n], 0, 0, 0);
    }
  }
#pragma unroll
  for (int r = 0; r < 4; r++) {
    float inv = 1.f / lsum[r];
    int row = b * S_ + q0 + lhi * 4 + r;
#pragma unroll
    for (int n = 0; n < 4; n++)
      conc[(size_t)row * (H_ * D_) + h * 64 + n * 16 + lane15] = f2b(o[n][r] * inv);
  }
}

// ------- layernorm over split-K partials: y = LN(Σ part + bias + resid) ------
template <int SK>
__global__ __launch_bounds__(256) void ln_red_kernel(
    const float* __restrict__ part, const float* __restrict__ bias,
    const float* __restrict__ resid, const float* __restrict__ g,
    const float* __restrict__ bsh, float* __restrict__ outf,
    ushort* __restrict__ outb) {
  int w = threadIdx.x >> 6, l = threadIdx.x & 63;
  int row = blockIdx.x * 4 + w;
  size_t off = (size_t)row * E_ + l * 8;
  float4 r0 = *(const float4*)(resid + off);
  float4 r1 = *(const float4*)(resid + off + 4);
  float4 bb0 = *(const float4*)(bias + l * 8);
  float4 bb1 = *(const float4*)(bias + l * 8 + 4);
  float x[8] = {r0.x + bb0.x, r0.y + bb0.y, r0.z + bb0.z, r0.w + bb0.w,
                r1.x + bb1.x, r1.y + bb1.y, r1.z + bb1.z, r1.w + bb1.w};
#pragma unroll
  for (int s = 0; s < SK; s++) {
    const float* ps = part + (size_t)s * M_ * E_ + off;
    float4 p0 = *(const float4*)ps;
    float4 p1 = *(const float4*)(ps + 4);
    x[0] += p0.x; x[1] += p0.y; x[2] += p0.z; x[3] += p0.w;
    x[4] += p1.x; x[5] += p1.y; x[6] += p1.z; x[7] += p1.w;
  }
  float s = 0.f, q = 0.f;
#pragma unroll
  for (int i = 0; i < 8; i++) { s += x[i]; q += x[i] * x[i]; }
#pragma unroll
  for (int off2 = 1; off2 < 64; off2 <<= 1) {
    s += __shfl_xor(s, off2);
    q += __shfl_xor(q, off2);
  }
  float mu = s * (1.f / 512.f);
  float var = q * (1.f / 512.f) - mu * mu;
  float rs = rsqrtf(var + 1e-5f);
  float4 g0 = *(const float4*)(g + l * 8);
  float4 g1 = *(const float4*)(g + l * 8 + 4);
  float4 b0 = *(const float4*)(bsh + l * 8);
  float4 b1 = *(const float4*)(bsh + l * 8 + 4);
  float gg[8] = {g0.x, g0.y, g0.z, g0.w, g1.x, g1.y, g1.z, g1.w};
  float bbv[8] = {b0.x, b0.y, b0.z, b0.w, b1.x, b1.y, b1.z, b1.w};
  float y[8];
#pragma unroll
  for (int i = 0; i < 8; i++) y[i] = (x[i] - mu) * rs * gg[i] + bbv[i];
  float* of = outf + off;
  *(float4*)of = make_float4(y[0], y[1], y[2], y[3]);
  *(float4*)(of + 4) = make_float4(y[4], y[5], y[6], y[7]);
  ushort4 u0 = {f2b(y[0]), f2b(y[1]), f2b(y[2]), f2b(y[3])};
  ushort4 u1 = {f2b(y[4]), f2b(y[5]), f2b(y[6]), f2b(y[7])};
  ushort* ob = outb + off;
  *(ushort4*)ob = u0;
  *(ushort4*)(ob + 4) = u1;
}

// ---------------- host ----------------
extern "C" void kernel_launch(void* const* d_in, const int* in_sizes, int n_in,
                              void* d_out, int out_size, void* d_ws, size_t ws_size,
                              hipStream_t stream) {
  const int* x = (const int*)d_in[0];
  const float* tok = (const float*)d_in[1];
  const float* pos = (const float*)d_in[2];
  const float* Wq = (const float*)d_in[3];
  const float* bq = (const float*)d_in[4];
  const float* Wk = (const float*)d_in[5];
  const float* bk = (const float*)d_in[6];
  const float* Wv = (const float*)d_in[7];
  const float* bv = (const float*)d_in[8];
  const float* Wo = (const float*)d_in[9];
  const float* bo = (const float*)d_in[10];
  const float* W1 = (const float*)d_in[11];
  const float* b1 = (const float*)d_in[12];
  const float* W2 = (const float*)d_in[13];
  const float* b2 = (const float*)d_in[14];
  const float* ln1g = (const float*)d_in[15];
  const float* ln1b = (const float*)d_in[16];
  const float* ln2g = (const float*)d_in[17];
  const float* ln2b = (const float*)d_in[18];
  const float* Wout = (const float*)d_in[19];
  const float* bout = (const float*)d_in[20];
  float* out = (float*)d_out;

  char* p = (char*)d_ws;
  auto alloc = [&](size_t bytes) {
    char* r = p;
    p += (bytes + 255) & ~(size_t)255;
    return r;
  };
  float* h_f = (float*)alloc((size_t)M_ * E_ * 4);
  ushort* h_b = (ushort*)alloc((size_t)M_ * E_ * 2);
  ushort* qkv_b = (ushort*)alloc((size_t)M_ * QKV_N * 2);
  ushort* conc_b = (ushort*)alloc((size_t)M_ * E_ * 2);
  float* part = (float*)alloc((size_t)4 * M_ * E_ * 4);   // split-K partials
  float* ln_f = (float*)alloc((size_t)M_ * E_ * 4);
  ushort* ln_b = (ushort*)alloc((size_t)M_ * E_ * 2);
  ushort* ff_b = (ushort*)alloc((size_t)M_ * FF_ * 2);
  ushort* vt_b = (ushort*)alloc((size_t)B_ * H_ * D_ * S_ * 2);
  ushort* wqkv = (ushort*)alloc((size_t)L_ * QKV_N * E_ * 2);
  float* bqkv = (float*)alloc((size_t)L_ * QKV_N * 4);
  ushort* wo_t = (ushort*)alloc((size_t)L_ * E_ * E_ * 2);
  ushort* w1_t = (ushort*)alloc((size_t)L_ * FF_ * E_ * 2);
  ushort* w2_t = (ushort*)alloc((size_t)L_ * E_ * FF_ * 2);
  ushort* wout_t = (ushort*)alloc((size_t)V_ * E_ * 2);

  // ---- weight conversion ----
  qkvw_kernel<<<dim3(E_ / 32, D_ / 32, 3 * L_ * H_), 256, 0, stream>>>(Wq, Wk, Wv, wqkv);
  transpose_cvt_kernel<<<dim3(16, 16, L_), 256, 0, stream>>>(
      Wo, wo_t, 512, 512, 1, (long long)512 * 512, 0, (long long)512 * 512, 0);
  transpose_cvt_kernel<<<dim3(E_ / 32, FF_ / 32, L_), 256, 0, stream>>>(
      W1, w1_t, E_, FF_, 1, (long long)E_ * FF_, 0, (long long)FF_ * E_, 0);
  transpose_cvt_kernel<<<dim3(FF_ / 32, E_ / 32, L_), 256, 0, stream>>>(
      W2, w2_t, FF_, E_, 1, (long long)FF_ * E_, 0, (long long)E_ * FF_, 0);
  transpose_cvt_kernel<<<dim3(E_ / 32, V_ / 32, 1), 256, 0, stream>>>(
      Wout, wout_t, E_, V_, 1, 0, 0, 0, 0);
  pack_b_kernel<<<(L_ * QKV_N + 255) / 256, 256, 0, stream>>>(bq, bk, bv, bqkv);

  // ---- embedding ----
  embed_kernel<<<(M_ * E_) / 256, 256, 0, stream>>>(x, tok, pos, h_f, h_b);

  for (int l = 0; l < L_; ++l) {
    // QKV: [2048,512] @ [512,1536] -> bf16 (+ fused V transpose into vt_b)
    mfma_gemm_kernel<true, false, true><<<(QKV_N / 128) * (M_ / 128), 256, 0, stream>>>(
        h_b, wqkv + (size_t)l * QKV_N * E_, bqkv + l * QKV_N, nullptr,
        qkv_b, vt_b, M_, QKV_N, E_, QKV_N / 128);
    // flash attention
    fattn_kernel<<<dim3(S_ / 32, B_ * H_), 128, 0, stream>>>(qkv_b, vt_b, conc_b);
    // Wo split-K=4 -> partials; LN1 fuses reduction + bias + residual(h_f)
    mfma_gemm_sk_kernel<4><<<4 * (E_ / 128) * (M_ / 128), 256, 0, stream>>>(
        conc_b, wo_t + (size_t)l * E_ * E_, part, M_, E_, E_, E_ / 128);
    ln_red_kernel<4><<<M_ / 4, 256, 0, stream>>>(
        part, bo + l * E_, h_f, ln1g + l * E_, ln1b + l * E_, ln_f, ln_b);
    // FF1 + ReLU: [2048,512] @ [512,2048] -> bf16
    mfma_gemm_kernel<true, true, false><<<(FF_ / 128) * (M_ / 128), 256, 0, stream>>>(
        ln_b, w1_t + (size_t)l * FF_ * E_, b1 + l * FF_, nullptr, ff_b, nullptr,
        M_, FF_, E_, FF_ / 128);
    // FF2 split-K=4 -> partials; LN2 fuses reduction + bias + residual(ln_f)
    mfma_gemm_sk_kernel<4><<<4 * (E_ / 128) * (M_ / 128), 256, 0, stream>>>(
        ff_b, w2_t + (size_t)l * E_ * FF_, part, M_, E_, FF_, E_ / 128);
    ln_red_kernel<4><<<M_ / 4, 256, 0, stream>>>(
        part, b2 + l * E_, ln_f, ln2g + l * E_, ln2b + l * E_, h_f, h_b);
  }

  // final projection: [2048,512] @ [512,32000] -> fp32 logits
  // 256^2 tile, 8 waves, double-buffered 2-phase, XCD-chunked (1000 blocks)
  mfma_gemm256_kernel<<<(M_ / 256) * (V_ / 256), 512, 0, stream>>>(
      h_b, wout_t, bout, out, M_, V_, E_);
}